// Round 1
// baseline (1532.347 us; speedup 1.0000x reference)
//
#include <hip/hip_runtime.h>
#include <hip/hip_bf16.h>
#include <math.h>

// Problem constants (from reference)
#define N_NODES   50000
#define N_EDGES   800000
#define EP        (N_EDGES + N_NODES)   // edges + self loops = 850000
#define IN_CH     128
#define HID       64
#define HEADS     4
#define F1        (HEADS * HID)         // 256
#define OUT_CH    10
#define NUM_GRAPHS 500
#define NEG_SLOPE 0.2f

// ---------------------------------------------------------------------------
// GEMM1: H1 = x @ W1  [50000,128]x[128,256] -> [50000,256]
// Also per-node attention logits al_s1/al_d1 [N,4] via in-wave reduction.
// One block per node, 256 threads (thread j -> output col j; wave w -> head w).
// ---------------------------------------------------------------------------
__global__ __launch_bounds__(256) void gemm1_kernel(
    const float* __restrict__ x, const float* __restrict__ W1,
    const float* __restrict__ a_src1, const float* __restrict__ a_dst1,
    float* __restrict__ H1, float* __restrict__ al_s1, float* __restrict__ al_d1)
{
    const int n = blockIdx.x;
    const int j = threadIdx.x;
    __shared__ float xr[IN_CH];
    if (j < IN_CH) xr[j] = x[(size_t)n * IN_CH + j];
    __syncthreads();
    float acc = 0.f;
    #pragma unroll 8
    for (int k = 0; k < IN_CH; ++k)
        acc += xr[k] * W1[k * F1 + j];        // coalesced across j; xr broadcast
    H1[(size_t)n * F1 + j] = acc;
    // attention logits: al_s1[n,h] = sum_{c} H1[n,h*64+c] * a_src1[h*64+c]
    float cs = acc * a_src1[j];
    float cd = acc * a_dst1[j];
    #pragma unroll
    for (int off = 32; off > 0; off >>= 1) {
        cs += __shfl_down(cs, off, 64);
        cd += __shfl_down(cd, off, 64);
    }
    if ((j & 63) == 0) {
        const int h = j >> 6;
        al_s1[n * HEADS + h] = cs;
        al_d1[n * HEADS + h] = cd;
    }
}

// ---------------------------------------------------------------------------
// Softmax denominator, layer 1. One thread per edge; 4 heads each.
// No max-subtraction: numerator & denominator scale identically -> same alpha.
// ---------------------------------------------------------------------------
__global__ void denom1_kernel(const int* __restrict__ ei,
    const float* __restrict__ al_s1, const float* __restrict__ al_d1,
    float* __restrict__ denom1)
{
    const int e = blockIdx.x * blockDim.x + threadIdx.x;
    if (e >= EP) return;
    int src, dst;
    if (e < N_EDGES) { src = ei[e]; dst = ei[N_EDGES + e]; }
    else             { src = dst = e - N_EDGES; }
    const float4 as = *(const float4*)(al_s1 + src * 4);
    const float4 ad = *(const float4*)(al_d1 + dst * 4);
    float ev[4] = {as.x + ad.x, as.y + ad.y, as.z + ad.z, as.w + ad.w};
    #pragma unroll
    for (int h = 0; h < 4; ++h) {
        float t = ev[h];
        t = t > 0.f ? t : NEG_SLOPE * t;
        atomicAdd(&denom1[dst * 4 + h], __expf(t));
    }
}

// ---------------------------------------------------------------------------
// Edge aggregation, layer 1. One wave-lane per (edge, channel); lane c handles
// channel c of all 4 heads. Coalesced 64-float atomic bursts per wave.
// ---------------------------------------------------------------------------
__global__ __launch_bounds__(256) void agg1_kernel(const int* __restrict__ ei,
    const float* __restrict__ al_s1, const float* __restrict__ al_d1,
    const float* __restrict__ denom1, const float* __restrict__ H1,
    float* __restrict__ out1)
{
    const long long gid = (long long)blockIdx.x * blockDim.x + threadIdx.x;
    const int e = (int)(gid >> 6);
    const int c = (int)(gid & 63);
    if (e >= EP) return;
    int src, dst;
    if (e < N_EDGES) { src = ei[e]; dst = ei[N_EDGES + e]; }
    else             { src = dst = e - N_EDGES; }
    const float4 as = *(const float4*)(al_s1 + src * 4);
    const float4 ad = *(const float4*)(al_d1 + dst * 4);
    const float4 dn = *(const float4*)(denom1 + dst * 4);
    float alpha[4];
    {
        float ev[4] = {as.x + ad.x, as.y + ad.y, as.z + ad.z, as.w + ad.w};
        float dd[4] = {dn.x, dn.y, dn.z, dn.w};
        #pragma unroll
        for (int h = 0; h < 4; ++h) {
            float t = ev[h];
            t = t > 0.f ? t : NEG_SLOPE * t;
            alpha[h] = __expf(t) / (dd[h] + 1e-16f);
        }
    }
    const size_t srow = (size_t)src * F1;
    const size_t drow = (size_t)dst * F1;
    #pragma unroll
    for (int h = 0; h < 4; ++h) {
        const float v = alpha[h] * H1[srow + h * 64 + c];
        atomicAdd(&out1[drow + h * 64 + c], v);
    }
}

// ---------------------------------------------------------------------------
// GEMM2: H2 = relu(out1 + b1) @ W2  [50000,256]x[256,64] -> [50000,64]
// One block per node, 64 threads. Also al_s2/al_d2 (H=1).
// ---------------------------------------------------------------------------
__global__ __launch_bounds__(64) void gemm2_kernel(
    const float* __restrict__ out1, const float* __restrict__ b1,
    const float* __restrict__ W2,
    const float* __restrict__ a_src2, const float* __restrict__ a_dst2,
    float* __restrict__ H2, float* __restrict__ al_s2, float* __restrict__ al_d2)
{
    const int n = blockIdx.x;
    const int j = threadIdx.x;
    __shared__ float r[F1];
    #pragma unroll
    for (int t = j; t < F1; t += 64) {
        const float v = out1[(size_t)n * F1 + t] + b1[t];
        r[t] = v > 0.f ? v : 0.f;
    }
    __syncthreads();
    float acc = 0.f;
    #pragma unroll 8
    for (int k = 0; k < F1; ++k)
        acc += r[k] * W2[k * HID + j];
    H2[(size_t)n * HID + j] = acc;
    float cs = acc * a_src2[j];
    float cd = acc * a_dst2[j];
    #pragma unroll
    for (int off = 32; off > 0; off >>= 1) {
        cs += __shfl_down(cs, off, 64);
        cd += __shfl_down(cd, off, 64);
    }
    if (j == 0) { al_s2[n] = cs; al_d2[n] = cd; }
}

// ---------------------------------------------------------------------------
// Softmax denominator, layer 2 (H=1). One thread per edge.
// ---------------------------------------------------------------------------
__global__ void denom2_kernel(const int* __restrict__ ei,
    const float* __restrict__ al_s2, const float* __restrict__ al_d2,
    float* __restrict__ denom2)
{
    const int e = blockIdx.x * blockDim.x + threadIdx.x;
    if (e >= EP) return;
    int src, dst;
    if (e < N_EDGES) { src = ei[e]; dst = ei[N_EDGES + e]; }
    else             { src = dst = e - N_EDGES; }
    float t = al_s2[src] + al_d2[dst];
    t = t > 0.f ? t : NEG_SLOPE * t;
    atomicAdd(&denom2[dst], __expf(t));
}

// ---------------------------------------------------------------------------
// Edge aggregation, layer 2. One lane per (edge, channel).
// ---------------------------------------------------------------------------
__global__ __launch_bounds__(256) void agg2_kernel(const int* __restrict__ ei,
    const float* __restrict__ al_s2, const float* __restrict__ al_d2,
    const float* __restrict__ denom2, const float* __restrict__ H2,
    float* __restrict__ out2)
{
    const long long gid = (long long)blockIdx.x * blockDim.x + threadIdx.x;
    const int e = (int)(gid >> 6);
    const int c = (int)(gid & 63);
    if (e >= EP) return;
    int src, dst;
    if (e < N_EDGES) { src = ei[e]; dst = ei[N_EDGES + e]; }
    else             { src = dst = e - N_EDGES; }
    float t = al_s2[src] + al_d2[dst];
    t = t > 0.f ? t : NEG_SLOPE * t;
    const float alpha = __expf(t) / (denom2[dst] + 1e-16f);
    atomicAdd(&out2[(size_t)dst * HID + c], alpha * H2[(size_t)src * HID + c]);
}

// ---------------------------------------------------------------------------
// Pool (global_add_pool via sorted-batch binary search) + FC + log_softmax.
// One block per graph, 64 threads. b2 folded in as count*b2.
// ---------------------------------------------------------------------------
__global__ __launch_bounds__(64) void pool_fc_kernel(
    const float* __restrict__ out2, const float* __restrict__ b2,
    const int* __restrict__ batch,
    const float* __restrict__ fc_w, const float* __restrict__ fc_b,
    float* __restrict__ out)
{
    const int g = blockIdx.x;
    const int c = threadIdx.x;
    __shared__ int se[2];
    if (c < 2) {
        const int target = g + c;  // lower_bound(batch, target)
        int lo = 0, hi = N_NODES;
        while (lo < hi) { int mid = (lo + hi) >> 1; if (batch[mid] < target) lo = mid + 1; else hi = mid; }
        se[c] = lo;
    }
    __syncthreads();
    const int start = se[0], end = se[1];
    float acc = 0.f;
    for (int n = start; n < end; ++n)
        acc += out2[(size_t)n * HID + c];
    acc += (float)(end - start) * b2[c];
    __shared__ float pooled[HID];
    pooled[c] = acc;
    __syncthreads();
    __shared__ float logits[OUT_CH];
    if (c < OUT_CH) {
        float l = fc_b[c];
        #pragma unroll
        for (int k = 0; k < HID; ++k) l += pooled[k] * fc_w[k * OUT_CH + c];
        logits[c] = l;
    }
    __syncthreads();
    if (c == 0) {
        float m = logits[0];
        #pragma unroll
        for (int j2 = 1; j2 < OUT_CH; ++j2) m = fmaxf(m, logits[j2]);
        float s = 0.f;
        #pragma unroll
        for (int j2 = 0; j2 < OUT_CH; ++j2) s += __expf(logits[j2] - m);
        const float lse = m + __logf(s);
        #pragma unroll
        for (int j2 = 0; j2 < OUT_CH; ++j2) out[g * OUT_CH + j2] = logits[j2] - lse;
    }
}

// ---------------------------------------------------------------------------

extern "C" void kernel_launch(void* const* d_in, const int* in_sizes, int n_in,
                              void* d_out, int out_size, void* d_ws, size_t ws_size,
                              hipStream_t stream)
{
    const float* x      = (const float*)d_in[0];
    const int*   ei     = (const int*)  d_in[1];   // [2, 800000] flat: src row, dst row
    const int*   batch  = (const int*)  d_in[2];
    const float* W1     = (const float*)d_in[3];
    const float* a_src1 = (const float*)d_in[4];
    const float* a_dst1 = (const float*)d_in[5];
    const float* b1     = (const float*)d_in[6];
    const float* W2     = (const float*)d_in[7];
    const float* a_src2 = (const float*)d_in[8];
    const float* a_dst2 = (const float*)d_in[9];
    const float* b2     = (const float*)d_in[10];
    const float* fc_w   = (const float*)d_in[11];
    const float* fc_b   = (const float*)d_in[12];
    float* out = (float*)d_out;

    float* ws = (float*)d_ws;
    size_t off = 0;
    float* H1     = ws + off; off += (size_t)N_NODES * F1;     // 12.8M f
    float* out1   = ws + off; off += (size_t)N_NODES * F1;     // 12.8M f
    float* al_s1  = ws + off; off += (size_t)N_NODES * HEADS;
    float* al_d1  = ws + off; off += (size_t)N_NODES * HEADS;
    float* denom1 = ws + off; off += (size_t)N_NODES * HEADS;
    float* H2     = ws + off; off += (size_t)N_NODES * HID;
    float* al_s2  = ws + off; off += (size_t)N_NODES;
    float* al_d2  = ws + off; off += (size_t)N_NODES;
    float* denom2 = ws + off; off += (size_t)N_NODES;
    float* out2   = ws + off; off += (size_t)N_NODES * HID;

    // zero the atomic accumulators (ws is re-poisoned 0xAA before every call)
    hipMemsetAsync(out1,   0, sizeof(float) * (size_t)N_NODES * F1,    stream);
    hipMemsetAsync(denom1, 0, sizeof(float) * (size_t)N_NODES * HEADS, stream);
    hipMemsetAsync(denom2, 0, sizeof(float) * (size_t)N_NODES,         stream);
    hipMemsetAsync(out2,   0, sizeof(float) * (size_t)N_NODES * HID,   stream);

    gemm1_kernel<<<N_NODES, 256, 0, stream>>>(x, W1, a_src1, a_dst1, H1, al_s1, al_d1);
    denom1_kernel<<<(EP + 255) / 256, 256, 0, stream>>>(ei, al_s1, al_d1, denom1);
    agg1_kernel<<<(int)(((long long)EP * 64 + 255) / 256), 256, 0, stream>>>(
        ei, al_s1, al_d1, denom1, H1, out1);
    gemm2_kernel<<<N_NODES, 64, 0, stream>>>(out1, b1, W2, a_src2, a_dst2, H2, al_s2, al_d2);
    denom2_kernel<<<(EP + 255) / 256, 256, 0, stream>>>(ei, al_s2, al_d2, denom2);
    agg2_kernel<<<(int)(((long long)EP * 64 + 255) / 256), 256, 0, stream>>>(
        ei, al_s2, al_d2, denom2, H2, out2);
    pool_fc_kernel<<<NUM_GRAPHS, 64, 0, stream>>>(out2, b2, batch, fc_w, fc_b, out);
}

// Round 3
// 635.619 us; speedup vs baseline: 2.4108x; 2.4108x over previous
//
#include <hip/hip_runtime.h>
#include <hip/hip_bf16.h>
#include <math.h>

// Problem constants (from reference)
#define N_NODES   50000
#define N_EDGES   800000
#define EP        (N_EDGES + N_NODES)   // edges + self loops = 850000
#define IN_CH     128
#define HID       64
#define HEADS     4
#define F1        (HEADS * HID)         // 256
#define OUT_CH    10
#define NUM_GRAPHS 500
#define NEG_SLOPE 0.2f

// ---------------------------------------------------------------------------
// CSR build: histogram of dst, block-wide scan, scatter src indices.
// ---------------------------------------------------------------------------
__global__ void csr_count(const int* __restrict__ ei, int* __restrict__ deg)
{
    const int e = blockIdx.x * blockDim.x + threadIdx.x;
    if (e >= EP) return;
    const int dst = (e < N_EDGES) ? ei[N_EDGES + e] : e - N_EDGES;
    atomicAdd(&deg[dst], 1);
}

#define SCAN_T 1024
__global__ __launch_bounds__(SCAN_T) void csr_scan(
    const int* __restrict__ deg, int* __restrict__ rowptr, int* __restrict__ cursor)
{
    __shared__ int part[SCAN_T];
    const int t = threadIdx.x;
    const int CH = (N_NODES + SCAN_T - 1) / SCAN_T;   // 49
    const int lo = t * CH;
    const int hi = min(lo + CH, N_NODES);
    int s = 0;
    for (int i = lo; i < hi; ++i) s += deg[i];
    part[t] = s;
    __syncthreads();
    for (int off = 1; off < SCAN_T; off <<= 1) {
        int v = (t >= off) ? part[t - off] : 0;
        __syncthreads();
        if (t >= off) part[t] += v;
        __syncthreads();
    }
    int run = (t == 0) ? 0 : part[t - 1];   // exclusive base
    for (int i = lo; i < hi; ++i) {
        rowptr[i] = run;
        cursor[i] = run;
        run += deg[i];
    }
    if (t == SCAN_T - 1) rowptr[N_NODES] = run;   // == EP
}

__global__ void csr_scatter(const int* __restrict__ ei,
                            int* __restrict__ cursor, int* __restrict__ csr_src)
{
    const int e = blockIdx.x * blockDim.x + threadIdx.x;
    if (e >= EP) return;
    int src, dst;
    if (e < N_EDGES) { src = ei[e]; dst = ei[N_EDGES + e]; }
    else             { src = dst = e - N_EDGES; }
    const int pos = atomicAdd(&cursor[dst], 1);
    csr_src[pos] = src;
}

// ---------------------------------------------------------------------------
// GEMM1: H1 = x @ W1  [50000,128]x[128,256]; 8 nodes/block so W1 is read once
// per 8 nodes (W1 traffic 6.4 GB -> 0.8 GB). Also al_s1/al_d1 [N,4].
// ---------------------------------------------------------------------------
#define NP1 8
__global__ __launch_bounds__(256) void gemm1_kernel(
    const float* __restrict__ x, const float* __restrict__ W1,
    const float* __restrict__ a_src1, const float* __restrict__ a_dst1,
    float* __restrict__ H1, float* __restrict__ al_s1, float* __restrict__ al_d1)
{
    const int nb = blockIdx.x * NP1;
    const int j = threadIdx.x;
    __shared__ float xs[NP1][IN_CH];
    #pragma unroll
    for (int t = j; t < NP1 * IN_CH; t += 256)
        xs[t >> 7][t & 127] = x[(size_t)nb * IN_CH + t];
    __syncthreads();
    float acc[NP1];
    #pragma unroll
    for (int n = 0; n < NP1; ++n) acc[n] = 0.f;
    #pragma unroll 4
    for (int k = 0; k < IN_CH; ++k) {
        const float w = W1[k * F1 + j];          // coalesced across j
        #pragma unroll
        for (int n = 0; n < NP1; ++n) acc[n] += xs[n][k] * w;  // LDS broadcast
    }
    const float asj = a_src1[j], adj = a_dst1[j];
    #pragma unroll
    for (int n = 0; n < NP1; ++n) {
        H1[(size_t)(nb + n) * F1 + j] = acc[n];
        float cs = acc[n] * asj;
        float cd = acc[n] * adj;
        #pragma unroll
        for (int off = 32; off > 0; off >>= 1) {
            cs += __shfl_down(cs, off, 64);
            cd += __shfl_down(cd, off, 64);
        }
        if ((j & 63) == 0) {
            const int h = j >> 6;
            al_s1[(nb + n) * HEADS + h] = cs;
            al_d1[(nb + n) * HEADS + h] = cd;
        }
    }
}

// ---------------------------------------------------------------------------
// Layer-1 aggregation, CSR gather. One wave per dst node; lane c handles
// channel c of all 4 heads. Accumulates un-normalized numerator + denominator
// (identical alpha to max-subtracted softmax), divides once, fuses +b1, relu.
// No atomics; out1r written exactly once (write traffic 870 MB -> 51 MB).
// ---------------------------------------------------------------------------
__global__ __launch_bounds__(64) void agg1_csr(
    const int* __restrict__ rowptr, const int* __restrict__ csr_src,
    const float* __restrict__ al_s1, const float* __restrict__ al_d1,
    const float* __restrict__ H1, const float* __restrict__ b1,
    float* __restrict__ out1r)
{
    const int dst = blockIdx.x;
    const int c = threadIdx.x;
    const int beg = rowptr[dst], end = rowptr[dst + 1];
    const float4 ad = *(const float4*)(al_d1 + dst * 4);
    float acc0 = 0.f, acc1 = 0.f, acc2 = 0.f, acc3 = 0.f;
    float den0 = 0.f, den1 = 0.f, den2 = 0.f, den3 = 0.f;
    for (int i = beg; i < end; ++i) {
        const int src = csr_src[i];                      // wave-uniform
        const float4 as = *(const float4*)(al_s1 + src * 4);
        float t0 = as.x + ad.x; t0 = t0 > 0.f ? t0 : NEG_SLOPE * t0;
        float t1 = as.y + ad.y; t1 = t1 > 0.f ? t1 : NEG_SLOPE * t1;
        float t2 = as.z + ad.z; t2 = t2 > 0.f ? t2 : NEG_SLOPE * t2;
        float t3 = as.w + ad.w; t3 = t3 > 0.f ? t3 : NEG_SLOPE * t3;
        const float w0 = __expf(t0), w1 = __expf(t1), w2 = __expf(t2), w3 = __expf(t3);
        const float* hrow = H1 + (size_t)src * F1;
        acc0 += w0 * hrow[c];
        acc1 += w1 * hrow[64 + c];
        acc2 += w2 * hrow[128 + c];
        acc3 += w3 * hrow[192 + c];
        den0 += w0; den1 += w1; den2 += w2; den3 += w3;
    }
    const size_t o = (size_t)dst * F1;
    float v;
    v = acc0 / (den0 + 1e-16f) + b1[c];       out1r[o + c]       = v > 0.f ? v : 0.f;
    v = acc1 / (den1 + 1e-16f) + b1[64 + c];  out1r[o + 64 + c]  = v > 0.f ? v : 0.f;
    v = acc2 / (den2 + 1e-16f) + b1[128 + c]; out1r[o + 128 + c] = v > 0.f ? v : 0.f;
    v = acc3 / (den3 + 1e-16f) + b1[192 + c]; out1r[o + 192 + c] = v > 0.f ? v : 0.f;
}

// ---------------------------------------------------------------------------
// GEMM2: H2 = out1r @ W2  [50000,256]x[256,64]; 8 nodes/block (W2 traffic
// 3.2 GB -> 0.4 GB). bias+relu already fused into out1r. Also al_s2/al_d2.
// ---------------------------------------------------------------------------
#define NP2 8
__global__ __launch_bounds__(64) void gemm2_kernel(
    const float* __restrict__ out1r, const float* __restrict__ W2,
    const float* __restrict__ a_src2, const float* __restrict__ a_dst2,
    float* __restrict__ H2, float* __restrict__ al_s2, float* __restrict__ al_d2)
{
    const int nb = blockIdx.x * NP2;
    const int j = threadIdx.x;
    __shared__ float rs[NP2][F1];
    #pragma unroll
    for (int t = j; t < NP2 * F1; t += 64)
        rs[t >> 8][t & 255] = out1r[(size_t)nb * F1 + t];
    __syncthreads();
    float acc[NP2];
    #pragma unroll
    for (int n = 0; n < NP2; ++n) acc[n] = 0.f;
    #pragma unroll 4
    for (int k = 0; k < F1; ++k) {
        const float w = W2[k * HID + j];
        #pragma unroll
        for (int n = 0; n < NP2; ++n) acc[n] += rs[n][k] * w;
    }
    const float asj = a_src2[j], adj = a_dst2[j];
    #pragma unroll
    for (int n = 0; n < NP2; ++n) {
        H2[(size_t)(nb + n) * HID + j] = acc[n];
        float cs = acc[n] * asj;
        float cd = acc[n] * adj;
        #pragma unroll
        for (int off = 32; off > 0; off >>= 1) {
            cs += __shfl_down(cs, off, 64);
            cd += __shfl_down(cd, off, 64);
        }
        if (j == 0) { al_s2[nb + n] = cs; al_d2[nb + n] = cd; }
    }
}

// ---------------------------------------------------------------------------
// Layer-2 aggregation, CSR gather (H=1). One wave per dst node.
// ---------------------------------------------------------------------------
__global__ __launch_bounds__(64) void agg2_csr(
    const int* __restrict__ rowptr, const int* __restrict__ csr_src,
    const float* __restrict__ al_s2, const float* __restrict__ al_d2,
    const float* __restrict__ H2, float* __restrict__ out2)
{
    const int dst = blockIdx.x;
    const int c = threadIdx.x;
    const int beg = rowptr[dst], end = rowptr[dst + 1];
    const float ad = al_d2[dst];
    float acc = 0.f, den = 0.f;
    for (int i = beg; i < end; ++i) {
        const int src = csr_src[i];
        float t = al_s2[src] + ad;
        t = t > 0.f ? t : NEG_SLOPE * t;
        const float w = __expf(t);
        acc += w * H2[(size_t)src * HID + c];
        den += w;
    }
    out2[(size_t)dst * HID + c] = acc / (den + 1e-16f);
}

// ---------------------------------------------------------------------------
// Pool (sorted-batch binary search) + FC + log_softmax. b2 folded as count*b2.
// ---------------------------------------------------------------------------
__global__ __launch_bounds__(64) void pool_fc_kernel(
    const float* __restrict__ out2, const float* __restrict__ b2,
    const int* __restrict__ batch,
    const float* __restrict__ fc_w, const float* __restrict__ fc_b,
    float* __restrict__ out)
{
    const int g = blockIdx.x;
    const int c = threadIdx.x;
    __shared__ int se[2];
    if (c < 2) {
        const int target = g + c;  // lower_bound(batch, target)
        int lo = 0, hi = N_NODES;
        while (lo < hi) { int mid = (lo + hi) >> 1; if (batch[mid] < target) lo = mid + 1; else hi = mid; }
        se[c] = lo;
    }
    __syncthreads();
    const int start = se[0], end = se[1];
    float acc = 0.f;
    for (int n = start; n < end; ++n)
        acc += out2[(size_t)n * HID + c];
    acc += (float)(end - start) * b2[c];
    __shared__ float pooled[HID];
    pooled[c] = acc;
    __syncthreads();
    __shared__ float logits[OUT_CH];
    if (c < OUT_CH) {
        float l = fc_b[c];
        #pragma unroll
        for (int k = 0; k < HID; ++k) l += pooled[k] * fc_w[k * OUT_CH + c];
        logits[c] = l;
    }
    __syncthreads();
    if (c == 0) {
        float m = logits[0];
        #pragma unroll
        for (int j2 = 1; j2 < OUT_CH; ++j2) m = fmaxf(m, logits[j2]);
        float s = 0.f;
        #pragma unroll
        for (int j2 = 0; j2 < OUT_CH; ++j2) s += __expf(logits[j2] - m);
        const float lse = m + __logf(s);
        #pragma unroll
        for (int j2 = 0; j2 < OUT_CH; ++j2) out[g * OUT_CH + j2] = logits[j2] - lse;
    }
}

// ---------------------------------------------------------------------------
// Workspace layout (aliased to stay well inside the proven ws budget):
//   [A] H1     51.2 MB  -- dead after agg1_csr; REUSED for H2/al_s2/al_d2/out2
//   [B] out1r  51.2 MB  -- dead after gemm2_kernel
//   [C] al_s1 + al_d1     1.6 MB
//   [D] CSR: deg/rowptr/cursor/csr_src  ~4.0 MB
// Peak ≈ 108 MB (round-0 layout used ~131 MB and ran fine).
// ---------------------------------------------------------------------------

extern "C" void kernel_launch(void* const* d_in, const int* in_sizes, int n_in,
                              void* d_out, int out_size, void* d_ws, size_t ws_size,
                              hipStream_t stream)
{
    const float* x      = (const float*)d_in[0];
    const int*   ei     = (const int*)  d_in[1];   // [2, 800000] flat: src row, dst row
    const int*   batch  = (const int*)  d_in[2];
    const float* W1     = (const float*)d_in[3];
    const float* a_src1 = (const float*)d_in[4];
    const float* a_dst1 = (const float*)d_in[5];
    const float* b1     = (const float*)d_in[6];
    const float* W2     = (const float*)d_in[7];
    const float* a_src2 = (const float*)d_in[8];
    const float* a_dst2 = (const float*)d_in[9];
    const float* b2     = (const float*)d_in[10];
    const float* fc_w   = (const float*)d_in[11];
    const float* fc_b   = (const float*)d_in[12];
    float* out = (float*)d_out;

    char* ws = (char*)d_ws;
    size_t off = 0;
    auto alloc_f = [&](size_t n) { float* p = (float*)(ws + off); off += n * 4; return p; };
    auto alloc_i = [&](size_t n) { int*   p = (int*)  (ws + off); off += n * 4; return p; };

    float* H1     = alloc_f((size_t)N_NODES * F1);   // region [A], 51.2 MB
    float* out1r  = alloc_f((size_t)N_NODES * F1);   // region [B], 51.2 MB
    float* al_s1  = alloc_f((size_t)N_NODES * HEADS);
    float* al_d1  = alloc_f((size_t)N_NODES * HEADS);
    int*   deg    = alloc_i(N_NODES);
    int*   rowptr = alloc_i(N_NODES + 1);
    int*   cursor = alloc_i(N_NODES);
    int*   csr_src= alloc_i(EP);                     // 3.4 MB

    // Layer-2 buffers alias region [A] (H1 is dead once agg1_csr completes;
    // stream ordering makes the reuse race-free).
    float* H2     = H1;                                         // 12.8 MB
    float* out2   = H1 + (size_t)N_NODES * HID;                 // 12.8 MB
    float* al_s2  = H1 + (size_t)2 * N_NODES * HID;             // 0.2 MB
    float* al_d2  = H1 + (size_t)2 * N_NODES * HID + N_NODES;   // 0.2 MB

    hipMemsetAsync(deg, 0, sizeof(int) * N_NODES, stream);

    // CSR build
    csr_count  <<<(EP + 255) / 256, 256, 0, stream>>>(ei, deg);
    csr_scan   <<<1, SCAN_T, 0, stream>>>(deg, rowptr, cursor);
    csr_scatter<<<(EP + 255) / 256, 256, 0, stream>>>(ei, cursor, csr_src);

    // Layer 1
    gemm1_kernel<<<N_NODES / NP1, 256, 0, stream>>>(x, W1, a_src1, a_dst1, H1, al_s1, al_d1);
    agg1_csr   <<<N_NODES, 64, 0, stream>>>(rowptr, csr_src, al_s1, al_d1, H1, b1, out1r);

    // Layer 2
    gemm2_kernel<<<N_NODES / NP2, 64, 0, stream>>>(out1r, W2, a_src2, a_dst2, H2, al_s2, al_d2);
    agg2_csr   <<<N_NODES, 64, 0, stream>>>(rowptr, csr_src, al_s2, al_d2, H2, out2);

    // Readout
    pool_fc_kernel<<<NUM_GRAPHS, 64, 0, stream>>>(out2, b2, batch, fc_w, fc_b, out);
}

// Round 4
// 582.080 us; speedup vs baseline: 2.6325x; 1.0920x over previous
//
#include <hip/hip_runtime.h>
#include <hip/hip_bf16.h>
#include <math.h>

// Problem constants (from reference)
#define N_NODES   50000
#define N_EDGES   800000
#define EP        (N_EDGES + N_NODES)   // edges + self loops = 850000
#define IN_CH     128
#define HID       64
#define HEADS     4
#define F1        (HEADS * HID)         // 256
#define OUT_CH    10
#define NUM_GRAPHS 500
#define NEG_SLOPE 0.2f

// bf16 pack/unpack helpers (RNE)
__device__ __forceinline__ unsigned short f2bf(float f) {
    unsigned int u = __float_as_uint(f);
    u += 0x7FFFu + ((u >> 16) & 1u);
    return (unsigned short)(u >> 16);
}
__device__ __forceinline__ unsigned int pack_bf2(float lo, float hi) {
    return (unsigned int)f2bf(lo) | ((unsigned int)f2bf(hi) << 16);
}
__device__ __forceinline__ float bf_lo(unsigned int u) { return __uint_as_float(u << 16); }
__device__ __forceinline__ float bf_hi(unsigned int u) { return __uint_as_float(u & 0xFFFF0000u); }
__device__ __forceinline__ float bf1(unsigned short h) { return __uint_as_float(((unsigned int)h) << 16); }

// ---------------------------------------------------------------------------
// CSR build: histogram of dst, block-wide scan, scatter src indices.
// ---------------------------------------------------------------------------
__global__ void csr_count(const int* __restrict__ ei, int* __restrict__ deg)
{
    const int e = blockIdx.x * blockDim.x + threadIdx.x;
    if (e >= EP) return;
    const int dst = (e < N_EDGES) ? ei[N_EDGES + e] : e - N_EDGES;
    atomicAdd(&deg[dst], 1);
}

#define SCAN_T 1024
__global__ __launch_bounds__(SCAN_T) void csr_scan(
    const int* __restrict__ deg, int* __restrict__ rowptr, int* __restrict__ cursor)
{
    __shared__ int part[SCAN_T];
    const int t = threadIdx.x;
    const int CH = (N_NODES + SCAN_T - 1) / SCAN_T;   // 49
    const int lo = t * CH;
    const int hi = min(lo + CH, N_NODES);
    int s = 0;
    for (int i = lo; i < hi; ++i) s += deg[i];
    part[t] = s;
    __syncthreads();
    for (int off = 1; off < SCAN_T; off <<= 1) {
        int v = (t >= off) ? part[t - off] : 0;
        __syncthreads();
        if (t >= off) part[t] += v;
        __syncthreads();
    }
    int run = (t == 0) ? 0 : part[t - 1];   // exclusive base
    for (int i = lo; i < hi; ++i) {
        rowptr[i] = run;
        cursor[i] = run;
        run += deg[i];
    }
    if (t == SCAN_T - 1) rowptr[N_NODES] = run;   // == EP
}

__global__ void csr_scatter(const int* __restrict__ ei,
                            int* __restrict__ cursor, int* __restrict__ csr_src)
{
    const int e = blockIdx.x * blockDim.x + threadIdx.x;
    if (e >= EP) return;
    int src, dst;
    if (e < N_EDGES) { src = ei[e]; dst = ei[N_EDGES + e]; }
    else             { src = dst = e - N_EDGES; }
    const int pos = atomicAdd(&cursor[dst], 1);
    csr_src[pos] = src;
}

// ---------------------------------------------------------------------------
// GEMM1: H1 = x @ W1  [50000,128]x[128,256]; 8 nodes/block (W1 L2-resident).
// fp32 compute; H1 stored bf16 (halves agg1's gather traffic). Attention
// logits al_s1/al_d1 [N,4] computed from fp32 acc (full precision).
// ---------------------------------------------------------------------------
#define NP1 8
__global__ __launch_bounds__(256) void gemm1_kernel(
    const float* __restrict__ x, const float* __restrict__ W1,
    const float* __restrict__ a_src1, const float* __restrict__ a_dst1,
    unsigned short* __restrict__ H1b, float* __restrict__ al_s1, float* __restrict__ al_d1)
{
    const int nb = blockIdx.x * NP1;
    const int j = threadIdx.x;
    __shared__ float xs[NP1][IN_CH];
    #pragma unroll
    for (int t = j; t < NP1 * IN_CH; t += 256)
        xs[t >> 7][t & 127] = x[(size_t)nb * IN_CH + t];
    __syncthreads();
    float acc[NP1];
    #pragma unroll
    for (int n = 0; n < NP1; ++n) acc[n] = 0.f;
    for (int k = 0; k < IN_CH; k += 4) {
        const float w0 = W1[(k + 0) * F1 + j];
        const float w1 = W1[(k + 1) * F1 + j];
        const float w2 = W1[(k + 2) * F1 + j];
        const float w3 = W1[(k + 3) * F1 + j];
        #pragma unroll
        for (int n = 0; n < NP1; ++n) {
            const float4 xv = *(const float4*)&xs[n][k];   // ds_read_b128
            acc[n] += xv.x * w0 + xv.y * w1 + xv.z * w2 + xv.w * w3;
        }
    }
    const float asj = a_src1[j], adj = a_dst1[j];
    #pragma unroll
    for (int n = 0; n < NP1; ++n) {
        H1b[(size_t)(nb + n) * F1 + j] = f2bf(acc[n]);
        float cs = acc[n] * asj;
        float cd = acc[n] * adj;
        #pragma unroll
        for (int off = 32; off > 0; off >>= 1) {
            cs += __shfl_down(cs, off, 64);
            cd += __shfl_down(cd, off, 64);
        }
        if ((j & 63) == 0) {
            const int h = j >> 6;
            al_s1[(nb + n) * HEADS + h] = cs;
            al_d1[(nb + n) * HEADS + h] = cd;
        }
    }
}

// ---------------------------------------------------------------------------
// Layer-1 aggregation, CSR gather, bf16 messages. One wave per dst node.
// H1b row = 128 uints (256 bf16). Lane l owns uints {l, 64+l} = channels
// {2l,2l+1} (head l>>5) and {128+2l,129+2l} (head 2+(l>>5)). Per-lane-half
// head ownership -> only 2 expf per edge. Epilogue fuses /den, +b1, relu and
// packs out1r as bf16 (halves gemm2 input traffic).
// ---------------------------------------------------------------------------
__global__ __launch_bounds__(64) void agg1_csr(
    const int* __restrict__ rowptr, const int* __restrict__ csr_src,
    const float* __restrict__ al_s1, const float* __restrict__ al_d1,
    const unsigned int* __restrict__ H1b, const float* __restrict__ b1,
    unsigned int* __restrict__ out1b)
{
    const int dst = blockIdx.x;
    const int l = threadIdx.x;
    const int half = l >> 5;                    // 0 or 1 (wave-half)
    const int beg = rowptr[dst], end = rowptr[dst + 1];
    const float4 ad = *(const float4*)(al_d1 + dst * 4);
    float a0 = 0.f, a1 = 0.f, a2 = 0.f, a3 = 0.f;
    float denA = 0.f, denB = 0.f;
    for (int i = beg; i < end; ++i) {
        const int src = csr_src[i];                       // wave-uniform
        const float4 as = *(const float4*)(al_s1 + src * 4);
        float t0 = as.x + ad.x; t0 = t0 > 0.f ? t0 : NEG_SLOPE * t0;
        float t1 = as.y + ad.y; t1 = t1 > 0.f ? t1 : NEG_SLOPE * t1;
        float t2 = as.z + ad.z; t2 = t2 > 0.f ? t2 : NEG_SLOPE * t2;
        float t3 = as.w + ad.w; t3 = t3 > 0.f ? t3 : NEG_SLOPE * t3;
        const float tA = half ? t1 : t0;                  // this half's heads
        const float tB = half ? t3 : t2;
        const float wA = __expf(tA), wB = __expf(tB);
        const unsigned int* hrow = H1b + (size_t)src * (F1 / 2);
        const unsigned int u1 = hrow[l];
        const unsigned int u2 = hrow[64 + l];
        a0 += wA * bf_lo(u1); a1 += wA * bf_hi(u1);
        a2 += wB * bf_lo(u2); a3 += wB * bf_hi(u2);
        denA += wA; denB += wB;
    }
    const float rA = 1.f / (denA + 1e-16f);
    const float rB = 1.f / (denB + 1e-16f);
    const float2 bA = *(const float2*)(b1 + 2 * l);        // channels 2l,2l+1
    const float2 bB = *(const float2*)(b1 + 128 + 2 * l);  // channels 128+2l,..
    float v0 = a0 * rA + bA.x; v0 = v0 > 0.f ? v0 : 0.f;
    float v1 = a1 * rA + bA.y; v1 = v1 > 0.f ? v1 : 0.f;
    float v2 = a2 * rB + bB.x; v2 = v2 > 0.f ? v2 : 0.f;
    float v3 = a3 * rB + bB.y; v3 = v3 > 0.f ? v3 : 0.f;
    unsigned int* orow = out1b + (size_t)dst * (F1 / 2);
    orow[l]      = pack_bf2(v0, v1);
    orow[64 + l] = pack_bf2(v2, v3);
}

// ---------------------------------------------------------------------------
// GEMM2: H2 = out1r @ W2  [50000,256]x[256,64]; 8 nodes/block. Input is bf16
// (unpacked to fp32 LDS), compute fp32, H2 stored bf16. Also al_s2/al_d2.
// ---------------------------------------------------------------------------
#define NP2 8
__global__ __launch_bounds__(64) void gemm2_kernel(
    const unsigned int* __restrict__ out1b, const float* __restrict__ W2,
    const float* __restrict__ a_src2, const float* __restrict__ a_dst2,
    unsigned short* __restrict__ H2b, float* __restrict__ al_s2, float* __restrict__ al_d2)
{
    const int nb = blockIdx.x * NP2;
    const int j = threadIdx.x;
    __shared__ float rs[NP2][F1];
    #pragma unroll
    for (int t = j; t < NP2 * F1 / 2; t += 64) {          // 1024 uints
        const unsigned int u = out1b[(size_t)nb * (F1 / 2) + t];
        const int n = t >> 7, p = t & 127;
        rs[n][2 * p]     = bf_lo(u);
        rs[n][2 * p + 1] = bf_hi(u);
    }
    __syncthreads();
    float acc[NP2];
    #pragma unroll
    for (int n = 0; n < NP2; ++n) acc[n] = 0.f;
    for (int k = 0; k < F1; k += 4) {
        const float w0 = W2[(k + 0) * HID + j];
        const float w1 = W2[(k + 1) * HID + j];
        const float w2 = W2[(k + 2) * HID + j];
        const float w3 = W2[(k + 3) * HID + j];
        #pragma unroll
        for (int n = 0; n < NP2; ++n) {
            const float4 rv = *(const float4*)&rs[n][k];   // ds_read_b128
            acc[n] += rv.x * w0 + rv.y * w1 + rv.z * w2 + rv.w * w3;
        }
    }
    const float asj = a_src2[j], adj = a_dst2[j];
    #pragma unroll
    for (int n = 0; n < NP2; ++n) {
        H2b[(size_t)(nb + n) * HID + j] = f2bf(acc[n]);
        float cs = acc[n] * asj;
        float cd = acc[n] * adj;
        #pragma unroll
        for (int off = 32; off > 0; off >>= 1) {
            cs += __shfl_down(cs, off, 64);
            cd += __shfl_down(cd, off, 64);
        }
        if (j == 0) { al_s2[nb + n] = cs; al_d2[nb + n] = cd; }
    }
}

// ---------------------------------------------------------------------------
// Layer-2 aggregation, CSR gather (H=1), bf16 messages. One wave per dst.
// ---------------------------------------------------------------------------
__global__ __launch_bounds__(64) void agg2_csr(
    const int* __restrict__ rowptr, const int* __restrict__ csr_src,
    const float* __restrict__ al_s2, const float* __restrict__ al_d2,
    const unsigned short* __restrict__ H2b, float* __restrict__ out2)
{
    const int dst = blockIdx.x;
    const int c = threadIdx.x;
    const int beg = rowptr[dst], end = rowptr[dst + 1];
    const float ad = al_d2[dst];
    float acc = 0.f, den = 0.f;
    for (int i = beg; i < end; ++i) {
        const int src = csr_src[i];
        float t = al_s2[src] + ad;
        t = t > 0.f ? t : NEG_SLOPE * t;
        const float w = __expf(t);
        acc += w * bf1(H2b[(size_t)src * HID + c]);
        den += w;
    }
    out2[(size_t)dst * HID + c] = acc / (den + 1e-16f);
}

// ---------------------------------------------------------------------------
// Pool (sorted-batch binary search) + FC + log_softmax. b2 folded as count*b2.
// ---------------------------------------------------------------------------
__global__ __launch_bounds__(64) void pool_fc_kernel(
    const float* __restrict__ out2, const float* __restrict__ b2,
    const int* __restrict__ batch,
    const float* __restrict__ fc_w, const float* __restrict__ fc_b,
    float* __restrict__ out)
{
    const int g = blockIdx.x;
    const int c = threadIdx.x;
    __shared__ int se[2];
    if (c < 2) {
        const int target = g + c;  // lower_bound(batch, target)
        int lo = 0, hi = N_NODES;
        while (lo < hi) { int mid = (lo + hi) >> 1; if (batch[mid] < target) lo = mid + 1; else hi = mid; }
        se[c] = lo;
    }
    __syncthreads();
    const int start = se[0], end = se[1];
    float acc = 0.f;
    for (int n = start; n < end; ++n)
        acc += out2[(size_t)n * HID + c];
    acc += (float)(end - start) * b2[c];
    __shared__ float pooled[HID];
    pooled[c] = acc;
    __syncthreads();
    __shared__ float logits[OUT_CH];
    if (c < OUT_CH) {
        float l = fc_b[c];
        #pragma unroll
        for (int k = 0; k < HID; ++k) l += pooled[k] * fc_w[k * OUT_CH + c];
        logits[c] = l;
    }
    __syncthreads();
    if (c == 0) {
        float m = logits[0];
        #pragma unroll
        for (int j2 = 1; j2 < OUT_CH; ++j2) m = fmaxf(m, logits[j2]);
        float s = 0.f;
        #pragma unroll
        for (int j2 = 0; j2 < OUT_CH; ++j2) s += __expf(logits[j2] - m);
        const float lse = m + __logf(s);
        #pragma unroll
        for (int j2 = 0; j2 < OUT_CH; ++j2) out[g * OUT_CH + j2] = logits[j2] - lse;
    }
}

// ---------------------------------------------------------------------------
// Workspace: H1b 25.6 + out1b 25.6 + al1 1.6 + H2b 6.4 + al2 0.4 + out2 12.8
//            + CSR 4.0  ≈ 76 MB  (round-0 layout used ~131 MB and ran fine)
// ---------------------------------------------------------------------------

extern "C" void kernel_launch(void* const* d_in, const int* in_sizes, int n_in,
                              void* d_out, int out_size, void* d_ws, size_t ws_size,
                              hipStream_t stream)
{
    const float* x      = (const float*)d_in[0];
    const int*   ei     = (const int*)  d_in[1];   // [2, 800000] flat: src row, dst row
    const int*   batch  = (const int*)  d_in[2];
    const float* W1     = (const float*)d_in[3];
    const float* a_src1 = (const float*)d_in[4];
    const float* a_dst1 = (const float*)d_in[5];
    const float* b1     = (const float*)d_in[6];
    const float* W2     = (const float*)d_in[7];
    const float* a_src2 = (const float*)d_in[8];
    const float* a_dst2 = (const float*)d_in[9];
    const float* b2     = (const float*)d_in[10];
    const float* fc_w   = (const float*)d_in[11];
    const float* fc_b   = (const float*)d_in[12];
    float* out = (float*)d_out;

    char* ws = (char*)d_ws;
    size_t off = 0;
    auto alloc_b = [&](size_t bytes) { void* p = (void*)(ws + off); off += (bytes + 15) & ~15ull; return p; };

    unsigned short* H1b  = (unsigned short*)alloc_b((size_t)N_NODES * F1 * 2);   // 25.6 MB
    unsigned int*   out1b= (unsigned int*)  alloc_b((size_t)N_NODES * (F1/2) * 4); // 25.6 MB
    float* al_s1  = (float*)alloc_b((size_t)N_NODES * HEADS * 4);
    float* al_d1  = (float*)alloc_b((size_t)N_NODES * HEADS * 4);
    unsigned short* H2b  = (unsigned short*)alloc_b((size_t)N_NODES * HID * 2);  // 6.4 MB
    float* al_s2  = (float*)alloc_b((size_t)N_NODES * 4);
    float* al_d2  = (float*)alloc_b((size_t)N_NODES * 4);
    float* out2   = (float*)alloc_b((size_t)N_NODES * HID * 4);                  // 12.8 MB
    int*   deg    = (int*)alloc_b((size_t)N_NODES * 4);
    int*   rowptr = (int*)alloc_b((size_t)(N_NODES + 1) * 4);
    int*   cursor = (int*)alloc_b((size_t)N_NODES * 4);
    int*   csr_src= (int*)alloc_b((size_t)EP * 4);                               // 3.4 MB

    hipMemsetAsync(deg, 0, sizeof(int) * N_NODES, stream);

    // CSR build
    csr_count  <<<(EP + 255) / 256, 256, 0, stream>>>(ei, deg);
    csr_scan   <<<1, SCAN_T, 0, stream>>>(deg, rowptr, cursor);
    csr_scatter<<<(EP + 255) / 256, 256, 0, stream>>>(ei, cursor, csr_src);

    // Layer 1
    gemm1_kernel<<<N_NODES / NP1, 256, 0, stream>>>(x, W1, a_src1, a_dst1, H1b, al_s1, al_d1);
    agg1_csr   <<<N_NODES, 64, 0, stream>>>(rowptr, csr_src, al_s1, al_d1,
                                            (const unsigned int*)H1b, b1, out1b);

    // Layer 2
    gemm2_kernel<<<N_NODES / NP2, 64, 0, stream>>>(out1b, W2, a_src2, a_dst2, H2b, al_s2, al_d2);
    agg2_csr   <<<N_NODES, 64, 0, stream>>>(rowptr, csr_src, al_s2, al_d2, H2b, out2);

    // Readout
    pool_fc_kernel<<<NUM_GRAPHS, 64, 0, stream>>>(out2, b2, batch, fc_w, fc_b, out);
}

// Round 5
// 489.027 us; speedup vs baseline: 3.1335x; 1.1903x over previous
//
#include <hip/hip_runtime.h>
#include <hip/hip_bf16.h>
#include <math.h>

// Problem constants (from reference)
#define N_NODES   50000
#define N_EDGES   800000
#define EP        (N_EDGES + N_NODES)   // edges + self loops = 850000
#define IN_CH     128
#define HID       64
#define HEADS     4
#define F1        (HEADS * HID)         // 256
#define OUT_CH    10
#define NUM_GRAPHS 500
#define NEG_SLOPE 0.2f

// bf16 pack/unpack helpers (RNE)
__device__ __forceinline__ unsigned short f2bf(float f) {
    unsigned int u = __float_as_uint(f);
    u += 0x7FFFu + ((u >> 16) & 1u);
    return (unsigned short)(u >> 16);
}
__device__ __forceinline__ unsigned int pack_bf2(float lo, float hi) {
    return (unsigned int)f2bf(lo) | ((unsigned int)f2bf(hi) << 16);
}
__device__ __forceinline__ float bf_lo(unsigned int u) { return __uint_as_float(u << 16); }
__device__ __forceinline__ float bf_hi(unsigned int u) { return __uint_as_float(u & 0xFFFF0000u); }
__device__ __forceinline__ float bf1(unsigned short h) { return __uint_as_float(((unsigned int)h) << 16); }

// ---------------------------------------------------------------------------
// CSR build: histogram of dst, two-pass parallel scan, scatter src indices.
// ---------------------------------------------------------------------------
__global__ void csr_count(const int* __restrict__ ei, int* __restrict__ deg)
{
    const int e = blockIdx.x * blockDim.x + threadIdx.x;
    if (e >= EP) return;
    const int dst = (e < N_EDGES) ? ei[N_EDGES + e] : e - N_EDGES;
    atomicAdd(&deg[dst], 1);
}

#define SCAN_B 196                       // ceil(50000 / 256)
// pass 1: per-256-chunk block reduction -> blocksum[SCAN_B]
__global__ __launch_bounds__(256) void csr_scan1(
    const int* __restrict__ deg, int* __restrict__ blocksum)
{
    const int b = blockIdx.x, t = threadIdx.x;
    const int i = b * 256 + t;
    __shared__ int sm[256];
    sm[t] = (i < N_NODES) ? deg[i] : 0;
    __syncthreads();
    for (int off = 128; off > 0; off >>= 1) {
        if (t < off) sm[t] += sm[t + off];
        __syncthreads();
    }
    if (t == 0) blocksum[b] = sm[0];
}
// pass 2: block b computes base = sum(blocksum[0..b)) then exclusive-scans
// its own 256-element chunk (Hillis-Steele) -> rowptr, cursor.
__global__ __launch_bounds__(256) void csr_scan2(
    const int* __restrict__ deg, const int* __restrict__ blocksum,
    int* __restrict__ rowptr, int* __restrict__ cursor)
{
    const int b = blockIdx.x, t = threadIdx.x;
    __shared__ int sm[256];
    sm[t] = (t < b) ? blocksum[t] : 0;     // b < SCAN_B <= 256
    __syncthreads();
    for (int off = 128; off > 0; off >>= 1) {
        if (t < off) sm[t] += sm[t + off];
        __syncthreads();
    }
    const int base = sm[0];
    __syncthreads();
    const int i = b * 256 + t;
    const int d = (i < N_NODES) ? deg[i] : 0;
    sm[t] = d;
    __syncthreads();
    for (int off = 1; off < 256; off <<= 1) {   // inclusive scan
        int u = (t >= off) ? sm[t - off] : 0;
        __syncthreads();
        if (t >= off) sm[t] += u;
        __syncthreads();
    }
    const int excl = base + sm[t] - d;
    if (i < N_NODES) { rowptr[i] = excl; cursor[i] = excl; }
    if (i == N_NODES - 1) rowptr[N_NODES] = excl + d;   // == EP
}

__global__ void csr_scatter(const int* __restrict__ ei,
                            int* __restrict__ cursor, int* __restrict__ csr_src)
{
    const int e = blockIdx.x * blockDim.x + threadIdx.x;
    if (e >= EP) return;
    int src, dst;
    if (e < N_EDGES) { src = ei[e]; dst = ei[N_EDGES + e]; }
    else             { src = dst = e - N_EDGES; }
    const int pos = atomicAdd(&cursor[dst], 1);
    csr_src[pos] = src;
}

// ---------------------------------------------------------------------------
// GEMM1: H1 = x @ W1  [50000,128]x[128,256]; 8 nodes/block (W1 L2-resident).
// fp32 compute; H1 stored bf16 (halves agg1's gather traffic). Attention
// logits al_s1/al_d1 [N,4] computed from fp32 acc (full precision).
// ---------------------------------------------------------------------------
#define NP1 8
__global__ __launch_bounds__(256) void gemm1_kernel(
    const float* __restrict__ x, const float* __restrict__ W1,
    const float* __restrict__ a_src1, const float* __restrict__ a_dst1,
    unsigned short* __restrict__ H1b, float* __restrict__ al_s1, float* __restrict__ al_d1)
{
    const int nb = blockIdx.x * NP1;
    const int j = threadIdx.x;
    __shared__ float xs[NP1][IN_CH];
    #pragma unroll
    for (int t = j; t < NP1 * IN_CH; t += 256)
        xs[t >> 7][t & 127] = x[(size_t)nb * IN_CH + t];
    __syncthreads();
    float acc[NP1];
    #pragma unroll
    for (int n = 0; n < NP1; ++n) acc[n] = 0.f;
    for (int k = 0; k < IN_CH; k += 4) {
        const float w0 = W1[(k + 0) * F1 + j];
        const float w1 = W1[(k + 1) * F1 + j];
        const float w2 = W1[(k + 2) * F1 + j];
        const float w3 = W1[(k + 3) * F1 + j];
        #pragma unroll
        for (int n = 0; n < NP1; ++n) {
            const float4 xv = *(const float4*)&xs[n][k];   // ds_read_b128
            acc[n] += xv.x * w0 + xv.y * w1 + xv.z * w2 + xv.w * w3;
        }
    }
    const float asj = a_src1[j], adj = a_dst1[j];
    #pragma unroll
    for (int n = 0; n < NP1; ++n) {
        H1b[(size_t)(nb + n) * F1 + j] = f2bf(acc[n]);
        float cs = acc[n] * asj;
        float cd = acc[n] * adj;
        #pragma unroll
        for (int off = 32; off > 0; off >>= 1) {
            cs += __shfl_down(cs, off, 64);
            cd += __shfl_down(cd, off, 64);
        }
        if ((j & 63) == 0) {
            const int h = j >> 6;
            al_s1[(nb + n) * HEADS + h] = cs;
            al_d1[(nb + n) * HEADS + h] = cd;
        }
    }
}

// ---------------------------------------------------------------------------
// Layer-1 aggregation, CSR gather, bf16 messages. One wave per dst node.
// H1b row = 128 uints (256 bf16). Lane l owns uints {l, 64+l} = channels
// {2l,2l+1} (head l>>5) and {128+2l,129+2l} (head 2+(l>>5)). Per-lane-half
// head ownership -> only 2 expf per edge. Epilogue fuses /den, +b1, relu and
// packs out1r as bf16 (halves gemm2 input traffic).
// ---------------------------------------------------------------------------
__global__ __launch_bounds__(64) void agg1_csr(
    const int* __restrict__ rowptr, const int* __restrict__ csr_src,
    const float* __restrict__ al_s1, const float* __restrict__ al_d1,
    const unsigned int* __restrict__ H1b, const float* __restrict__ b1,
    unsigned int* __restrict__ out1b)
{
    const int dst = blockIdx.x;
    const int l = threadIdx.x;
    const int half = l >> 5;                    // 0 or 1 (wave-half)
    const int beg = rowptr[dst], end = rowptr[dst + 1];
    const float4 ad = *(const float4*)(al_d1 + dst * 4);
    float a0 = 0.f, a1 = 0.f, a2 = 0.f, a3 = 0.f;
    float denA = 0.f, denB = 0.f;
    for (int i = beg; i < end; ++i) {
        const int src = csr_src[i];                       // wave-uniform
        const float4 as = *(const float4*)(al_s1 + src * 4);
        float t0 = as.x + ad.x; t0 = t0 > 0.f ? t0 : NEG_SLOPE * t0;
        float t1 = as.y + ad.y; t1 = t1 > 0.f ? t1 : NEG_SLOPE * t1;
        float t2 = as.z + ad.z; t2 = t2 > 0.f ? t2 : NEG_SLOPE * t2;
        float t3 = as.w + ad.w; t3 = t3 > 0.f ? t3 : NEG_SLOPE * t3;
        const float tA = half ? t1 : t0;                  // this half's heads
        const float tB = half ? t3 : t2;
        const float wA = __expf(tA), wB = __expf(tB);
        const unsigned int* hrow = H1b + (size_t)src * (F1 / 2);
        const unsigned int u1 = hrow[l];
        const unsigned int u2 = hrow[64 + l];
        a0 += wA * bf_lo(u1); a1 += wA * bf_hi(u1);
        a2 += wB * bf_lo(u2); a3 += wB * bf_hi(u2);
        denA += wA; denB += wB;
    }
    const float rA = 1.f / (denA + 1e-16f);
    const float rB = 1.f / (denB + 1e-16f);
    const float2 bA = *(const float2*)(b1 + 2 * l);        // channels 2l,2l+1
    const float2 bB = *(const float2*)(b1 + 128 + 2 * l);  // channels 128+2l,..
    float v0 = a0 * rA + bA.x; v0 = v0 > 0.f ? v0 : 0.f;
    float v1 = a1 * rA + bA.y; v1 = v1 > 0.f ? v1 : 0.f;
    float v2 = a2 * rB + bB.x; v2 = v2 > 0.f ? v2 : 0.f;
    float v3 = a3 * rB + bB.y; v3 = v3 > 0.f ? v3 : 0.f;
    unsigned int* orow = out1b + (size_t)dst * (F1 / 2);
    orow[l]      = pack_bf2(v0, v1);
    orow[64 + l] = pack_bf2(v2, v3);
}

// ---------------------------------------------------------------------------
// GEMM2: H2 = out1r @ W2  [50000,256]x[256,64]; 8 nodes/block. Input is bf16
// (unpacked to fp32 LDS), compute fp32, H2 stored bf16. Also al_s2/al_d2.
// ---------------------------------------------------------------------------
#define NP2 8
__global__ __launch_bounds__(64) void gemm2_kernel(
    const unsigned int* __restrict__ out1b, const float* __restrict__ W2,
    const float* __restrict__ a_src2, const float* __restrict__ a_dst2,
    unsigned short* __restrict__ H2b, float* __restrict__ al_s2, float* __restrict__ al_d2)
{
    const int nb = blockIdx.x * NP2;
    const int j = threadIdx.x;
    __shared__ float rs[NP2][F1];
    #pragma unroll
    for (int t = j; t < NP2 * F1 / 2; t += 64) {          // 1024 uints
        const unsigned int u = out1b[(size_t)nb * (F1 / 2) + t];
        const int n = t >> 7, p = t & 127;
        rs[n][2 * p]     = bf_lo(u);
        rs[n][2 * p + 1] = bf_hi(u);
    }
    __syncthreads();
    float acc[NP2];
    #pragma unroll
    for (int n = 0; n < NP2; ++n) acc[n] = 0.f;
    for (int k = 0; k < F1; k += 4) {
        const float w0 = W2[(k + 0) * HID + j];
        const float w1 = W2[(k + 1) * HID + j];
        const float w2 = W2[(k + 2) * HID + j];
        const float w3 = W2[(k + 3) * HID + j];
        #pragma unroll
        for (int n = 0; n < NP2; ++n) {
            const float4 rv = *(const float4*)&rs[n][k];   // ds_read_b128
            acc[n] += rv.x * w0 + rv.y * w1 + rv.z * w2 + rv.w * w3;
        }
    }
    const float asj = a_src2[j], adj = a_dst2[j];
    #pragma unroll
    for (int n = 0; n < NP2; ++n) {
        H2b[(size_t)(nb + n) * HID + j] = f2bf(acc[n]);
        float cs = acc[n] * asj;
        float cd = acc[n] * adj;
        #pragma unroll
        for (int off = 32; off > 0; off >>= 1) {
            cs += __shfl_down(cs, off, 64);
            cd += __shfl_down(cd, off, 64);
        }
        if (j == 0) { al_s2[nb + n] = cs; al_d2[nb + n] = cd; }
    }
}

// ---------------------------------------------------------------------------
// Layer-2 aggregation, CSR gather (H=1), bf16 messages. One wave per dst.
// ---------------------------------------------------------------------------
__global__ __launch_bounds__(64) void agg2_csr(
    const int* __restrict__ rowptr, const int* __restrict__ csr_src,
    const float* __restrict__ al_s2, const float* __restrict__ al_d2,
    const unsigned short* __restrict__ H2b, float* __restrict__ out2)
{
    const int dst = blockIdx.x;
    const int c = threadIdx.x;
    const int beg = rowptr[dst], end = rowptr[dst + 1];
    const float ad = al_d2[dst];
    float acc = 0.f, den = 0.f;
    for (int i = beg; i < end; ++i) {
        const int src = csr_src[i];
        float t = al_s2[src] + ad;
        t = t > 0.f ? t : NEG_SLOPE * t;
        const float w = __expf(t);
        acc += w * bf1(H2b[(size_t)src * HID + c]);
        den += w;
    }
    out2[(size_t)dst * HID + c] = acc / (den + 1e-16f);
}

// ---------------------------------------------------------------------------
// Pool (sorted-batch binary search) + FC + log_softmax. b2 folded as count*b2.
// ---------------------------------------------------------------------------
__global__ __launch_bounds__(64) void pool_fc_kernel(
    const float* __restrict__ out2, const float* __restrict__ b2,
    const int* __restrict__ batch,
    const float* __restrict__ fc_w, const float* __restrict__ fc_b,
    float* __restrict__ out)
{
    const int g = blockIdx.x;
    const int c = threadIdx.x;
    __shared__ int se[2];
    if (c < 2) {
        const int target = g + c;  // lower_bound(batch, target)
        int lo = 0, hi = N_NODES;
        while (lo < hi) { int mid = (lo + hi) >> 1; if (batch[mid] < target) lo = mid + 1; else hi = mid; }
        se[c] = lo;
    }
    __syncthreads();
    const int start = se[0], end = se[1];
    float acc = 0.f;
    for (int n = start; n < end; ++n)
        acc += out2[(size_t)n * HID + c];
    acc += (float)(end - start) * b2[c];
    __shared__ float pooled[HID];
    pooled[c] = acc;
    __syncthreads();
    __shared__ float logits[OUT_CH];
    if (c < OUT_CH) {
        float l = fc_b[c];
        #pragma unroll
        for (int k = 0; k < HID; ++k) l += pooled[k] * fc_w[k * OUT_CH + c];
        logits[c] = l;
    }
    __syncthreads();
    if (c == 0) {
        float m = logits[0];
        #pragma unroll
        for (int j2 = 1; j2 < OUT_CH; ++j2) m = fmaxf(m, logits[j2]);
        float s = 0.f;
        #pragma unroll
        for (int j2 = 0; j2 < OUT_CH; ++j2) s += __expf(logits[j2] - m);
        const float lse = m + __logf(s);
        #pragma unroll
        for (int j2 = 0; j2 < OUT_CH; ++j2) out[g * OUT_CH + j2] = logits[j2] - lse;
    }
}

// ---------------------------------------------------------------------------
// Workspace ≈ 76 MB (round-0 layout used ~131 MB and ran fine)
// ---------------------------------------------------------------------------

extern "C" void kernel_launch(void* const* d_in, const int* in_sizes, int n_in,
                              void* d_out, int out_size, void* d_ws, size_t ws_size,
                              hipStream_t stream)
{
    const float* x      = (const float*)d_in[0];
    const int*   ei     = (const int*)  d_in[1];   // [2, 800000] flat: src row, dst row
    const int*   batch  = (const int*)  d_in[2];
    const float* W1     = (const float*)d_in[3];
    const float* a_src1 = (const float*)d_in[4];
    const float* a_dst1 = (const float*)d_in[5];
    const float* b1     = (const float*)d_in[6];
    const float* W2     = (const float*)d_in[7];
    const float* a_src2 = (const float*)d_in[8];
    const float* a_dst2 = (const float*)d_in[9];
    const float* b2     = (const float*)d_in[10];
    const float* fc_w   = (const float*)d_in[11];
    const float* fc_b   = (const float*)d_in[12];
    float* out = (float*)d_out;

    char* ws = (char*)d_ws;
    size_t off = 0;
    auto alloc_b = [&](size_t bytes) { void* p = (void*)(ws + off); off += (bytes + 15) & ~15ull; return p; };

    unsigned short* H1b  = (unsigned short*)alloc_b((size_t)N_NODES * F1 * 2);   // 25.6 MB
    unsigned int*   out1b= (unsigned int*)  alloc_b((size_t)N_NODES * (F1/2) * 4); // 25.6 MB
    float* al_s1  = (float*)alloc_b((size_t)N_NODES * HEADS * 4);
    float* al_d1  = (float*)alloc_b((size_t)N_NODES * HEADS * 4);
    unsigned short* H2b  = (unsigned short*)alloc_b((size_t)N_NODES * HID * 2);  // 6.4 MB
    float* al_s2  = (float*)alloc_b((size_t)N_NODES * 4);
    float* al_d2  = (float*)alloc_b((size_t)N_NODES * 4);
    float* out2   = (float*)alloc_b((size_t)N_NODES * HID * 4);                  // 12.8 MB
    int*   deg    = (int*)alloc_b((size_t)N_NODES * 4);
    int*   rowptr = (int*)alloc_b((size_t)(N_NODES + 1) * 4);
    int*   cursor = (int*)alloc_b((size_t)N_NODES * 4);
    int*   csr_src= (int*)alloc_b((size_t)EP * 4);                               // 3.4 MB
    int*   blocksum = (int*)alloc_b((size_t)SCAN_B * 4);

    hipMemsetAsync(deg, 0, sizeof(int) * N_NODES, stream);

    // CSR build (two-pass parallel scan; old single-block scan was 110 us)
    csr_count  <<<(EP + 255) / 256, 256, 0, stream>>>(ei, deg);
    csr_scan1  <<<SCAN_B, 256, 0, stream>>>(deg, blocksum);
    csr_scan2  <<<SCAN_B, 256, 0, stream>>>(deg, blocksum, rowptr, cursor);
    csr_scatter<<<(EP + 255) / 256, 256, 0, stream>>>(ei, cursor, csr_src);

    // Layer 1
    gemm1_kernel<<<N_NODES / NP1, 256, 0, stream>>>(x, W1, a_src1, a_dst1, H1b, al_s1, al_d1);
    agg1_csr   <<<N_NODES, 64, 0, stream>>>(rowptr, csr_src, al_s1, al_d1,
                                            (const unsigned int*)H1b, b1, out1b);

    // Layer 2
    gemm2_kernel<<<N_NODES / NP2, 64, 0, stream>>>(out1b, W2, a_src2, a_dst2, H2b, al_s2, al_d2);
    agg2_csr   <<<N_NODES, 64, 0, stream>>>(rowptr, csr_src, al_s2, al_d2, H2b, out2);

    // Readout
    pool_fc_kernel<<<NUM_GRAPHS, 64, 0, stream>>>(out2, b2, batch, fc_w, fc_b, out);
}

// Round 6
// 413.654 us; speedup vs baseline: 3.7044x; 1.1822x over previous
//
#include <hip/hip_runtime.h>
#include <hip/hip_bf16.h>
#include <math.h>

// Problem constants (from reference)
#define N_NODES   50000
#define N_EDGES   800000
#define EP        (N_EDGES + N_NODES)   // edges + self loops = 850000
#define IN_CH     128
#define HID       64
#define HEADS     4
#define F1        (HEADS * HID)         // 256
#define OUT_CH    10
#define NUM_GRAPHS 500
#define NEG_SLOPE 0.2f

typedef __attribute__((ext_vector_type(8))) short short8;   // 8 bf16 (4 VGPRs)
typedef __attribute__((ext_vector_type(4))) float floatx4;  // MFMA C/D

// bf16 pack/unpack helpers (RNE)
__device__ __forceinline__ unsigned short f2bf(float f) {
    unsigned int u = __float_as_uint(f);
    u += 0x7FFFu + ((u >> 16) & 1u);
    return (unsigned short)(u >> 16);
}
__device__ __forceinline__ unsigned int pack_bf2(float lo, float hi) {
    return (unsigned int)f2bf(lo) | ((unsigned int)f2bf(hi) << 16);
}
__device__ __forceinline__ float bf_lo(unsigned int u) { return __uint_as_float(u << 16); }
__device__ __forceinline__ float bf_hi(unsigned int u) { return __uint_as_float(u & 0xFFFF0000u); }
__device__ __forceinline__ float bf1(unsigned short h) { return __uint_as_float(((unsigned int)h) << 16); }

// ---------------------------------------------------------------------------
// CSR build: histogram of dst, two-pass parallel scan, scatter src indices.
// ---------------------------------------------------------------------------
__global__ void csr_count(const int* __restrict__ ei, int* __restrict__ deg)
{
    const int e = blockIdx.x * blockDim.x + threadIdx.x;
    if (e >= EP) return;
    const int dst = (e < N_EDGES) ? ei[N_EDGES + e] : e - N_EDGES;
    atomicAdd(&deg[dst], 1);
}

#define SCAN_B 196                       // ceil(50000 / 256)
__global__ __launch_bounds__(256) void csr_scan1(
    const int* __restrict__ deg, int* __restrict__ blocksum)
{
    const int b = blockIdx.x, t = threadIdx.x;
    const int i = b * 256 + t;
    __shared__ int sm[256];
    sm[t] = (i < N_NODES) ? deg[i] : 0;
    __syncthreads();
    for (int off = 128; off > 0; off >>= 1) {
        if (t < off) sm[t] += sm[t + off];
        __syncthreads();
    }
    if (t == 0) blocksum[b] = sm[0];
}
__global__ __launch_bounds__(256) void csr_scan2(
    const int* __restrict__ deg, const int* __restrict__ blocksum,
    int* __restrict__ rowptr, int* __restrict__ cursor)
{
    const int b = blockIdx.x, t = threadIdx.x;
    __shared__ int sm[256];
    sm[t] = (t < b) ? blocksum[t] : 0;     // b < SCAN_B <= 256
    __syncthreads();
    for (int off = 128; off > 0; off >>= 1) {
        if (t < off) sm[t] += sm[t + off];
        __syncthreads();
    }
    const int base = sm[0];
    __syncthreads();
    const int i = b * 256 + t;
    const int d = (i < N_NODES) ? deg[i] : 0;
    sm[t] = d;
    __syncthreads();
    for (int off = 1; off < 256; off <<= 1) {   // inclusive scan
        int u = (t >= off) ? sm[t - off] : 0;
        __syncthreads();
        if (t >= off) sm[t] += u;
        __syncthreads();
    }
    const int excl = base + sm[t] - d;
    if (i < N_NODES) { rowptr[i] = excl; cursor[i] = excl; }
    if (i == N_NODES - 1) rowptr[N_NODES] = excl + d;   // == EP
}

__global__ void csr_scatter(const int* __restrict__ ei,
                            int* __restrict__ cursor, int* __restrict__ csr_src)
{
    const int e = blockIdx.x * blockDim.x + threadIdx.x;
    if (e >= EP) return;
    int src, dst;
    if (e < N_EDGES) { src = ei[e]; dst = ei[N_EDGES + e]; }
    else             { src = dst = e - N_EDGES; }
    const int pos = atomicAdd(&cursor[dst], 1);
    csr_src[pos] = src;
}

// ---------------------------------------------------------------------------
// Prep: x (fp32) -> xb (bf16 row-major). 1.6M float4 -> uint2.
// ---------------------------------------------------------------------------
__global__ void conv_x(const float4* __restrict__ x4, uint2* __restrict__ xb2)
{
    const int i = blockIdx.x * blockDim.x + threadIdx.x;   // < N*IN_CH/4
    const float4 v = x4[i];
    xb2[i] = make_uint2(pack_bf2(v.x, v.y), pack_bf2(v.z, v.w));
}

// ---------------------------------------------------------------------------
// Prep: pack W (fp32 row-major [K][N]) into MFMA B-fragment layout, bf16:
// Wp[(ntile*KT + ktile)*64 + lane][j] = W[ktile*32 + (lane>>4)*8 + j][ntile*16 + (lane&15)]
// One thread per (ntile, ktile, lane); 8 elements each.
// ---------------------------------------------------------------------------
__global__ void pack_w1(const float* __restrict__ W1, unsigned short* __restrict__ W1p)
{
    const int gid = blockIdx.x * blockDim.x + threadIdx.x;   // < 16*4*64 = 4096
    const int t = gid >> 8, kt = (gid >> 6) & 3, l = gid & 63;
    const int col = t * 16 + (l & 15);
    unsigned short* o = W1p + (size_t)((t * 4 + kt) * 64 + l) * 8;
    #pragma unroll
    for (int j = 0; j < 8; ++j) {
        const int k = kt * 32 + (l >> 4) * 8 + j;
        o[j] = f2bf(W1[k * F1 + col]);
    }
}
__global__ void pack_w2(const float* __restrict__ W2, unsigned short* __restrict__ W2p)
{
    const int gid = blockIdx.x * blockDim.x + threadIdx.x;   // < 4*8*64 = 2048
    const int t = gid >> 9, kt = (gid >> 6) & 7, l = gid & 63;
    const int col = t * 16 + (l & 15);
    unsigned short* o = W2p + (size_t)((t * 8 + kt) * 64 + l) * 8;
    #pragma unroll
    for (int j = 0; j < 8; ++j) {
        const int k = kt * 32 + (l >> 4) * 8 + j;
        o[j] = f2bf(W2[k * HID + col]);
    }
}

// ---------------------------------------------------------------------------
// GEMM1 via MFMA: H1b = xb @ W1  [50000,128]x[128,256] bf16 -> bf16.
// Block = 16 nodes, 4 waves; wave w owns n-tiles w*4..w*4+3. K-loop 4 tiles.
// A-frag: lane l holds A[m=l&15][k=(l>>4)*8+j] -> contiguous 16B from xb row.
// B-frag: one 16B load from packed W1p. C/D: col=l&15, row=(l>>4)*4+reg.
// ---------------------------------------------------------------------------
__global__ __launch_bounds__(256) void gemm1_mfma(
    const short* __restrict__ xb, const short* __restrict__ W1p,
    unsigned short* __restrict__ H1b)
{
    const int m0 = blockIdx.x * 16;
    const int w = threadIdx.x >> 6;
    const int l = threadIdx.x & 63;
    const int q = l >> 4, r = l & 15;
    floatx4 acc[4] = {};
    const short* arow = xb + (size_t)(m0 + r) * IN_CH + q * 8;
    #pragma unroll
    for (int kt = 0; kt < 4; ++kt) {
        const short8 a = *(const short8*)(arow + kt * 32);
        #pragma unroll
        for (int t = 0; t < 4; ++t) {
            const int nt = w * 4 + t;
            const short8 b = *(const short8*)(W1p + (size_t)((nt * 4 + kt) * 64 + l) * 8);
            acc[t] = __builtin_amdgcn_mfma_f32_16x16x32_bf16(a, b, acc[t], 0, 0, 0);
        }
    }
    #pragma unroll
    for (int t = 0; t < 4; ++t) {
        const int col = (w * 4 + t) * 16 + r;
        #pragma unroll
        for (int reg = 0; reg < 4; ++reg)
            H1b[(size_t)(m0 + q * 4 + reg) * F1 + col] = f2bf(acc[t][reg]);
    }
}

// ---------------------------------------------------------------------------
// Logits layer 1 from H1b: al_s1[n,h] = sum_c H1[n,h*64+c]*a_src1[h*64+c].
// 4 waves/block = 4 nodes; lane l covers channels {2l,2l+1} (head l>>5) and
// {128+2l,129+2l} (head 2+(l>>5)); width-32 shuffle reduce.
// ---------------------------------------------------------------------------
__global__ __launch_bounds__(256) void logit1_kernel(
    const unsigned int* __restrict__ H1bu,
    const float* __restrict__ a_src1, const float* __restrict__ a_dst1,
    float* __restrict__ al_s1, float* __restrict__ al_d1)
{
    const int n = blockIdx.x * 4 + (threadIdx.x >> 6);
    const int l = threadIdx.x & 63;
    const unsigned int* row = H1bu + (size_t)n * (F1 / 2);
    const unsigned int u1 = row[l];
    const unsigned int u2 = row[64 + l];
    const float x0 = bf_lo(u1), x1 = bf_hi(u1), x2 = bf_lo(u2), x3 = bf_hi(u2);
    float ps1 = x0 * a_src1[2 * l]       + x1 * a_src1[2 * l + 1];
    float ps2 = x2 * a_src1[128 + 2 * l] + x3 * a_src1[129 + 2 * l];
    float pd1 = x0 * a_dst1[2 * l]       + x1 * a_dst1[2 * l + 1];
    float pd2 = x2 * a_dst1[128 + 2 * l] + x3 * a_dst1[129 + 2 * l];
    #pragma unroll
    for (int off = 16; off > 0; off >>= 1) {     // reduce within 32-lane halves
        ps1 += __shfl_down(ps1, off, 32);
        ps2 += __shfl_down(ps2, off, 32);
        pd1 += __shfl_down(pd1, off, 32);
        pd2 += __shfl_down(pd2, off, 32);
    }
    if ((l & 31) == 0) {
        const int h = l >> 5;                     // 0 or 1
        al_s1[n * 4 + h]     = ps1;
        al_s1[n * 4 + 2 + h] = ps2;
        al_d1[n * 4 + h]     = pd1;
        al_d1[n * 4 + 2 + h] = pd2;
    }
}

// ---------------------------------------------------------------------------
// Layer-1 aggregation, CSR gather, bf16 messages. One wave per dst node.
// Epilogue fuses /den, +b1, relu; out1b is row-major bf16 [N,256] (feeds
// gemm2_mfma's A operand directly).
// ---------------------------------------------------------------------------
__global__ __launch_bounds__(64) void agg1_csr(
    const int* __restrict__ rowptr, const int* __restrict__ csr_src,
    const float* __restrict__ al_s1, const float* __restrict__ al_d1,
    const unsigned int* __restrict__ H1b, const float* __restrict__ b1,
    unsigned int* __restrict__ out1b)
{
    const int dst = blockIdx.x;
    const int l = threadIdx.x;
    const int half = l >> 5;                    // 0 or 1 (wave-half)
    const int beg = rowptr[dst], end = rowptr[dst + 1];
    const float4 ad = *(const float4*)(al_d1 + dst * 4);
    float a0 = 0.f, a1 = 0.f, a2 = 0.f, a3 = 0.f;
    float denA = 0.f, denB = 0.f;
    for (int i = beg; i < end; ++i) {
        const int src = csr_src[i];                       // wave-uniform
        const float4 as = *(const float4*)(al_s1 + src * 4);
        float t0 = as.x + ad.x; t0 = t0 > 0.f ? t0 : NEG_SLOPE * t0;
        float t1 = as.y + ad.y; t1 = t1 > 0.f ? t1 : NEG_SLOPE * t1;
        float t2 = as.z + ad.z; t2 = t2 > 0.f ? t2 : NEG_SLOPE * t2;
        float t3 = as.w + ad.w; t3 = t3 > 0.f ? t3 : NEG_SLOPE * t3;
        const float tA = half ? t1 : t0;                  // this half's heads
        const float tB = half ? t3 : t2;
        const float wA = __expf(tA), wB = __expf(tB);
        const unsigned int* hrow = H1b + (size_t)src * (F1 / 2);
        const unsigned int u1 = hrow[l];
        const unsigned int u2 = hrow[64 + l];
        a0 += wA * bf_lo(u1); a1 += wA * bf_hi(u1);
        a2 += wB * bf_lo(u2); a3 += wB * bf_hi(u2);
        denA += wA; denB += wB;
    }
    const float rA = 1.f / (denA + 1e-16f);
    const float rB = 1.f / (denB + 1e-16f);
    const float2 bA = *(const float2*)(b1 + 2 * l);        // channels 2l,2l+1
    const float2 bB = *(const float2*)(b1 + 128 + 2 * l);  // channels 128+2l,..
    float v0 = a0 * rA + bA.x; v0 = v0 > 0.f ? v0 : 0.f;
    float v1 = a1 * rA + bA.y; v1 = v1 > 0.f ? v1 : 0.f;
    float v2 = a2 * rB + bB.x; v2 = v2 > 0.f ? v2 : 0.f;
    float v3 = a3 * rB + bB.y; v3 = v3 > 0.f ? v3 : 0.f;
    unsigned int* orow = out1b + (size_t)dst * (F1 / 2);
    orow[l]      = pack_bf2(v0, v1);
    orow[64 + l] = pack_bf2(v2, v3);
}

// ---------------------------------------------------------------------------
// GEMM2 via MFMA: H2b = out1b @ W2  [50000,256]x[256,64] bf16 -> bf16.
// Block = 16 nodes, 4 waves; wave w owns n-tile w (16 cols). K-loop 8 tiles.
// ---------------------------------------------------------------------------
__global__ __launch_bounds__(256) void gemm2_mfma(
    const short* __restrict__ out1s, const short* __restrict__ W2p,
    unsigned short* __restrict__ H2b)
{
    const int m0 = blockIdx.x * 16;
    const int w = threadIdx.x >> 6;
    const int l = threadIdx.x & 63;
    const int q = l >> 4, r = l & 15;
    floatx4 acc = {};
    const short* arow = out1s + (size_t)(m0 + r) * F1 + q * 8;
    #pragma unroll
    for (int kt = 0; kt < 8; ++kt) {
        const short8 a = *(const short8*)(arow + kt * 32);
        const short8 b = *(const short8*)(W2p + (size_t)((w * 8 + kt) * 64 + l) * 8);
        acc = __builtin_amdgcn_mfma_f32_16x16x32_bf16(a, b, acc, 0, 0, 0);
    }
    const int col = w * 16 + r;
    #pragma unroll
    for (int reg = 0; reg < 4; ++reg)
        H2b[(size_t)(m0 + q * 4 + reg) * HID + col] = f2bf(acc[reg]);
}

// ---------------------------------------------------------------------------
// Logits layer 2 from H2b (H=1): one wave per node, width-64 reduce.
// ---------------------------------------------------------------------------
__global__ __launch_bounds__(256) void logit2_kernel(
    const unsigned short* __restrict__ H2b,
    const float* __restrict__ a_src2, const float* __restrict__ a_dst2,
    float* __restrict__ al_s2, float* __restrict__ al_d2)
{
    const int n = blockIdx.x * 4 + (threadIdx.x >> 6);
    const int c = threadIdx.x & 63;
    const float h = bf1(H2b[(size_t)n * HID + c]);
    float ps = h * a_src2[c];
    float pd = h * a_dst2[c];
    #pragma unroll
    for (int off = 32; off > 0; off >>= 1) {
        ps += __shfl_down(ps, off, 64);
        pd += __shfl_down(pd, off, 64);
    }
    if (c == 0) { al_s2[n] = ps; al_d2[n] = pd; }
}

// ---------------------------------------------------------------------------
// Layer-2 aggregation, CSR gather (H=1), bf16 messages. One wave per dst.
// ---------------------------------------------------------------------------
__global__ __launch_bounds__(64) void agg2_csr(
    const int* __restrict__ rowptr, const int* __restrict__ csr_src,
    const float* __restrict__ al_s2, const float* __restrict__ al_d2,
    const unsigned short* __restrict__ H2b, float* __restrict__ out2)
{
    const int dst = blockIdx.x;
    const int c = threadIdx.x;
    const int beg = rowptr[dst], end = rowptr[dst + 1];
    const float ad = al_d2[dst];
    float acc = 0.f, den = 0.f;
    for (int i = beg; i < end; ++i) {
        const int src = csr_src[i];
        float t = al_s2[src] + ad;
        t = t > 0.f ? t : NEG_SLOPE * t;
        const float w = __expf(t);
        acc += w * bf1(H2b[(size_t)src * HID + c]);
        den += w;
    }
    out2[(size_t)dst * HID + c] = acc / (den + 1e-16f);
}

// ---------------------------------------------------------------------------
// Pool (sorted-batch binary search) + FC + log_softmax. b2 folded as count*b2.
// ---------------------------------------------------------------------------
__global__ __launch_bounds__(64) void pool_fc_kernel(
    const float* __restrict__ out2, const float* __restrict__ b2,
    const int* __restrict__ batch,
    const float* __restrict__ fc_w, const float* __restrict__ fc_b,
    float* __restrict__ out)
{
    const int g = blockIdx.x;
    const int c = threadIdx.x;
    __shared__ int se[2];
    if (c < 2) {
        const int target = g + c;  // lower_bound(batch, target)
        int lo = 0, hi = N_NODES;
        while (lo < hi) { int mid = (lo + hi) >> 1; if (batch[mid] < target) lo = mid + 1; else hi = mid; }
        se[c] = lo;
    }
    __syncthreads();
    const int start = se[0], end = se[1];
    float acc = 0.f;
    for (int n = start; n < end; ++n)
        acc += out2[(size_t)n * HID + c];
    acc += (float)(end - start) * b2[c];
    __shared__ float pooled[HID];
    pooled[c] = acc;
    __syncthreads();
    __shared__ float logits[OUT_CH];
    if (c < OUT_CH) {
        float l = fc_b[c];
        #pragma unroll
        for (int k = 0; k < HID; ++k) l += pooled[k] * fc_w[k * OUT_CH + c];
        logits[c] = l;
    }
    __syncthreads();
    if (c == 0) {
        float m = logits[0];
        #pragma unroll
        for (int j2 = 1; j2 < OUT_CH; ++j2) m = fmaxf(m, logits[j2]);
        float s = 0.f;
        #pragma unroll
        for (int j2 = 0; j2 < OUT_CH; ++j2) s += __expf(logits[j2] - m);
        const float lse = m + __logf(s);
        #pragma unroll
        for (int j2 = 0; j2 < OUT_CH; ++j2) out[g * OUT_CH + j2] = logits[j2] - lse;
    }
}

// ---------------------------------------------------------------------------
// Workspace ≈ 90 MB (round-0 layout used ~131 MB and ran fine)
// ---------------------------------------------------------------------------

extern "C" void kernel_launch(void* const* d_in, const int* in_sizes, int n_in,
                              void* d_out, int out_size, void* d_ws, size_t ws_size,
                              hipStream_t stream)
{
    const float* x      = (const float*)d_in[0];
    const int*   ei     = (const int*)  d_in[1];   // [2, 800000] flat: src row, dst row
    const int*   batch  = (const int*)  d_in[2];
    const float* W1     = (const float*)d_in[3];
    const float* a_src1 = (const float*)d_in[4];
    const float* a_dst1 = (const float*)d_in[5];
    const float* b1     = (const float*)d_in[6];
    const float* W2     = (const float*)d_in[7];
    const float* a_src2 = (const float*)d_in[8];
    const float* a_dst2 = (const float*)d_in[9];
    const float* b2     = (const float*)d_in[10];
    const float* fc_w   = (const float*)d_in[11];
    const float* fc_b   = (const float*)d_in[12];
    float* out = (float*)d_out;

    char* ws = (char*)d_ws;
    size_t off = 0;
    auto alloc_b = [&](size_t bytes) { void* p = (void*)(ws + off); off += (bytes + 15) & ~15ull; return p; };

    unsigned short* H1b  = (unsigned short*)alloc_b((size_t)N_NODES * F1 * 2);     // 25.6 MB
    unsigned int*   out1b= (unsigned int*)  alloc_b((size_t)N_NODES * (F1/2) * 4); // 25.6 MB
    float* al_s1  = (float*)alloc_b((size_t)N_NODES * HEADS * 4);
    float* al_d1  = (float*)alloc_b((size_t)N_NODES * HEADS * 4);
    unsigned short* H2b  = (unsigned short*)alloc_b((size_t)N_NODES * HID * 2);    // 6.4 MB
    float* al_s2  = (float*)alloc_b((size_t)N_NODES * 4);
    float* al_d2  = (float*)alloc_b((size_t)N_NODES * 4);
    float* out2   = (float*)alloc_b((size_t)N_NODES * HID * 4);                    // 12.8 MB
    int*   deg    = (int*)alloc_b((size_t)N_NODES * 4);
    int*   rowptr = (int*)alloc_b((size_t)(N_NODES + 1) * 4);
    int*   cursor = (int*)alloc_b((size_t)N_NODES * 4);
    int*   csr_src= (int*)alloc_b((size_t)EP * 4);                                 // 3.4 MB
    int*   blocksum = (int*)alloc_b((size_t)SCAN_B * 4);
    short* xb     = (short*)alloc_b((size_t)N_NODES * IN_CH * 2);                  // 12.8 MB
    unsigned short* W1p = (unsigned short*)alloc_b((size_t)IN_CH * F1 * 2);        // 64 KB
    unsigned short* W2p = (unsigned short*)alloc_b((size_t)F1 * HID * 2);          // 32 KB

    hipMemsetAsync(deg, 0, sizeof(int) * N_NODES, stream);

    // Prep (independent of CSR)
    conv_x <<<(N_NODES * IN_CH / 4) / 256, 256, 0, stream>>>((const float4*)x, (uint2*)xb);
    pack_w1<<<16, 256, 0, stream>>>(W1, W1p);
    pack_w2<<<8, 256, 0, stream>>>(W2, W2p);

    // CSR build (two-pass parallel scan)
    csr_count  <<<(EP + 255) / 256, 256, 0, stream>>>(ei, deg);
    csr_scan1  <<<SCAN_B, 256, 0, stream>>>(deg, blocksum);
    csr_scan2  <<<SCAN_B, 256, 0, stream>>>(deg, blocksum, rowptr, cursor);
    csr_scatter<<<(EP + 255) / 256, 256, 0, stream>>>(ei, cursor, csr_src);

    // Layer 1
    gemm1_mfma   <<<N_NODES / 16, 256, 0, stream>>>(xb, (const short*)W1p, H1b);
    logit1_kernel<<<N_NODES / 4, 256, 0, stream>>>((const unsigned int*)H1b, a_src1, a_dst1, al_s1, al_d1);
    agg1_csr     <<<N_NODES, 64, 0, stream>>>(rowptr, csr_src, al_s1, al_d1,
                                              (const unsigned int*)H1b, b1, out1b);

    // Layer 2
    gemm2_mfma   <<<N_NODES / 16, 256, 0, stream>>>((const short*)out1b, (const short*)W2p, H2b);
    logit2_kernel<<<N_NODES / 4, 256, 0, stream>>>(H2b, a_src2, a_dst2, al_s2, al_d2);
    agg2_csr     <<<N_NODES, 64, 0, stream>>>(rowptr, csr_src, al_s2, al_d2, H2b, out2);

    // Readout
    pool_fc_kernel<<<NUM_GRAPHS, 64, 0, stream>>>(out2, b2, batch, fc_w, fc_b, out);
}

// Round 8
// 358.260 us; speedup vs baseline: 4.2772x; 1.1546x over previous
//
#include <hip/hip_runtime.h>
#include <hip/hip_bf16.h>
#include <math.h>

// Problem constants (from reference)
#define N_NODES   50000
#define N_EDGES   800000
#define EP        (N_EDGES + N_NODES)   // edges + self loops = 850000
#define IN_CH     128
#define HID       64
#define HEADS     4
#define F1        (HEADS * HID)         // 256
#define OUT_CH    10
#define NUM_GRAPHS 500
#define NEG_SLOPE 0.2f
#define CHUNK     64                     // edges staged per LDS prepass

typedef __attribute__((ext_vector_type(8))) short short8;   // 8 bf16 (4 VGPRs)
typedef __attribute__((ext_vector_type(4))) float floatx4;  // MFMA C/D

// bf16 pack/unpack helpers (RNE)
__device__ __forceinline__ unsigned short f2bf(float f) {
    unsigned int u = __float_as_uint(f);
    u += 0x7FFFu + ((u >> 16) & 1u);
    return (unsigned short)(u >> 16);
}
__device__ __forceinline__ unsigned int pack_bf2(float lo, float hi) {
    return (unsigned int)f2bf(lo) | ((unsigned int)f2bf(hi) << 16);
}
__device__ __forceinline__ float bf_lo(unsigned int u) { return __uint_as_float(u << 16); }
__device__ __forceinline__ float bf_hi(unsigned int u) { return __uint_as_float(u & 0xFFFF0000u); }
__device__ __forceinline__ float bf1(unsigned short h) { return __uint_as_float(((unsigned int)h) << 16); }

// ---------------------------------------------------------------------------
// CSR build: histogram of dst, two-pass parallel scan, scatter src indices.
// ---------------------------------------------------------------------------
__global__ void csr_count(const int* __restrict__ ei, int* __restrict__ deg)
{
    const int e = blockIdx.x * blockDim.x + threadIdx.x;
    if (e >= EP) return;
    const int dst = (e < N_EDGES) ? ei[N_EDGES + e] : e - N_EDGES;
    atomicAdd(&deg[dst], 1);
}

#define SCAN_B 196                       // ceil(50000 / 256)
__global__ __launch_bounds__(256) void csr_scan1(
    const int* __restrict__ deg, int* __restrict__ blocksum)
{
    const int b = blockIdx.x, t = threadIdx.x;
    const int i = b * 256 + t;
    __shared__ int sm[256];
    sm[t] = (i < N_NODES) ? deg[i] : 0;
    __syncthreads();
    for (int off = 128; off > 0; off >>= 1) {
        if (t < off) sm[t] += sm[t + off];
        __syncthreads();
    }
    if (t == 0) blocksum[b] = sm[0];
}
__global__ __launch_bounds__(256) void csr_scan2(
    const int* __restrict__ deg, const int* __restrict__ blocksum,
    int* __restrict__ rowptr, int* __restrict__ cursor)
{
    const int b = blockIdx.x, t = threadIdx.x;
    __shared__ int sm[256];
    sm[t] = (t < b) ? blocksum[t] : 0;     // b < SCAN_B <= 256
    __syncthreads();
    for (int off = 128; off > 0; off >>= 1) {
        if (t < off) sm[t] += sm[t + off];
        __syncthreads();
    }
    const int base = sm[0];
    __syncthreads();
    const int i = b * 256 + t;
    const int d = (i < N_NODES) ? deg[i] : 0;
    sm[t] = d;
    __syncthreads();
    for (int off = 1; off < 256; off <<= 1) {   // inclusive scan
        int u = (t >= off) ? sm[t - off] : 0;
        __syncthreads();
        if (t >= off) sm[t] += u;
        __syncthreads();
    }
    const int excl = base + sm[t] - d;
    if (i < N_NODES) { rowptr[i] = excl; cursor[i] = excl; }
    if (i == N_NODES - 1) rowptr[N_NODES] = excl + d;   // == EP
}

__global__ void csr_scatter(const int* __restrict__ ei,
                            int* __restrict__ cursor, int* __restrict__ csr_src)
{
    const int e = blockIdx.x * blockDim.x + threadIdx.x;
    if (e >= EP) return;
    int src, dst;
    if (e < N_EDGES) { src = ei[e]; dst = ei[N_EDGES + e]; }
    else             { src = dst = e - N_EDGES; }
    const int pos = atomicAdd(&cursor[dst], 1);
    csr_src[pos] = src;
}

// ---------------------------------------------------------------------------
// Prep: x (fp32) -> xb (bf16 row-major). 1.6M float4 -> uint2.
// ---------------------------------------------------------------------------
__global__ void conv_x(const float4* __restrict__ x4, uint2* __restrict__ xb2)
{
    const int i = blockIdx.x * blockDim.x + threadIdx.x;   // < N*IN_CH/4
    const float4 v = x4[i];
    xb2[i] = make_uint2(pack_bf2(v.x, v.y), pack_bf2(v.z, v.w));
}

// ---------------------------------------------------------------------------
// Prep: pack W (fp32 row-major [K][N]) into MFMA B-fragment layout, bf16:
// Wp[(ntile*KT + ktile)*64 + lane][j] = W[ktile*32 + (lane>>4)*8 + j][ntile*16 + (lane&15)]
// ---------------------------------------------------------------------------
__global__ void pack_w1(const float* __restrict__ W1, unsigned short* __restrict__ W1p)
{
    const int gid = blockIdx.x * blockDim.x + threadIdx.x;   // < 16*4*64 = 4096
    const int t = gid >> 8, kt = (gid >> 6) & 3, l = gid & 63;
    const int col = t * 16 + (l & 15);
    unsigned short* o = W1p + (size_t)((t * 4 + kt) * 64 + l) * 8;
    #pragma unroll
    for (int j = 0; j < 8; ++j) {
        const int k = kt * 32 + (l >> 4) * 8 + j;
        o[j] = f2bf(W1[k * F1 + col]);
    }
}
__global__ void pack_w2(const float* __restrict__ W2, unsigned short* __restrict__ W2p)
{
    const int gid = blockIdx.x * blockDim.x + threadIdx.x;   // < 4*8*64 = 2048
    const int t = gid >> 9, kt = (gid >> 6) & 7, l = gid & 63;
    const int col = t * 16 + (l & 15);
    unsigned short* o = W2p + (size_t)((t * 8 + kt) * 64 + l) * 8;
    #pragma unroll
    for (int j = 0; j < 8; ++j) {
        const int k = kt * 32 + (l >> 4) * 8 + j;
        o[j] = f2bf(W2[k * HID + col]);
    }
}

// ---------------------------------------------------------------------------
// GEMM1 via MFMA + fused layer-1 logits. Block = 16 nodes, 4 waves; wave w
// owns n-tiles w*4..w*4+3 = cols w*64..w*64+63 = exactly head w, so the
// al_s1/al_d1 reduction stays within the wave (width-16 shuffle over cols).
// ---------------------------------------------------------------------------
__global__ __launch_bounds__(256) void gemm1_mfma(
    const short* __restrict__ xb, const short* __restrict__ W1p,
    const float* __restrict__ a_src1, const float* __restrict__ a_dst1,
    unsigned short* __restrict__ H1b,
    float* __restrict__ al_s1, float* __restrict__ al_d1)
{
    const int m0 = blockIdx.x * 16;
    const int w = threadIdx.x >> 6;
    const int l = threadIdx.x & 63;
    const int q = l >> 4, r = l & 15;
    floatx4 acc[4] = {};
    const short* arow = xb + (size_t)(m0 + r) * IN_CH + q * 8;
    #pragma unroll
    for (int kt = 0; kt < 4; ++kt) {
        const short8 a = *(const short8*)(arow + kt * 32);
        #pragma unroll
        for (int t = 0; t < 4; ++t) {
            const int nt = w * 4 + t;
            const short8 b = *(const short8*)(W1p + (size_t)((nt * 4 + kt) * 64 + l) * 8);
            acc[t] = __builtin_amdgcn_mfma_f32_16x16x32_bf16(a, b, acc[t], 0, 0, 0);
        }
    }
    float ls[4] = {0.f, 0.f, 0.f, 0.f}, ld[4] = {0.f, 0.f, 0.f, 0.f};
    #pragma unroll
    for (int t = 0; t < 4; ++t) {
        const int col = (w * 4 + t) * 16 + r;
        const float as = a_src1[col], ad = a_dst1[col];
        #pragma unroll
        for (int reg = 0; reg < 4; ++reg) {
            H1b[(size_t)(m0 + q * 4 + reg) * F1 + col] = f2bf(acc[t][reg]);
            ls[reg] += acc[t][reg] * as;
            ld[reg] += acc[t][reg] * ad;
        }
    }
    #pragma unroll
    for (int reg = 0; reg < 4; ++reg) {
        #pragma unroll
        for (int off = 8; off > 0; off >>= 1) {     // reduce over 16 cols
            ls[reg] += __shfl_down(ls[reg], off, 16);
            ld[reg] += __shfl_down(ld[reg], off, 16);
        }
    }
    if (r == 0) {
        #pragma unroll
        for (int reg = 0; reg < 4; ++reg) {
            const int n = m0 + q * 4 + reg;
            al_s1[n * HEADS + w] = ls[reg];
            al_d1[n * HEADS + w] = ld[reg];
        }
    }
}

// ---------------------------------------------------------------------------
// Layer-1 aggregation, CSR gather, bf16 messages. One wave per dst node.
// Per 64-edge chunk: prepass lane i computes the 4 head-weights of edge i
// ONCE (was: every lane recomputed 2 expf per edge -> 64x redundant VALU),
// stashed in LDS swizzled [w0,w2,w1,w3] so each wave-half reads its (wA,wB)
// pair with one b64 broadcast. Epilogue fuses /den, +b1, relu -> bf16.
// ---------------------------------------------------------------------------
__global__ __launch_bounds__(64) void agg1_csr(
    const int* __restrict__ rowptr, const int* __restrict__ csr_src,
    const float* __restrict__ al_s1, const float* __restrict__ al_d1,
    const unsigned int* __restrict__ H1b, const float* __restrict__ b1,
    unsigned int* __restrict__ out1b)
{
    const int dst = blockIdx.x;
    const int l = threadIdx.x;
    const int half = l >> 5;                    // 0 or 1 (wave-half)
    const int beg = rowptr[dst], end = rowptr[dst + 1];
    __shared__ int   sL[CHUNK];
    __shared__ float wL[CHUNK][4];              // [w0,w2,w1,w3]
    const float4 ad = *(const float4*)(al_d1 + dst * 4);
    float a0 = 0.f, a1 = 0.f, a2 = 0.f, a3 = 0.f;
    float denA = 0.f, denB = 0.f;
    for (int base = beg; base < end; base += CHUNK) {
        const int n = min(CHUNK, end - base);
        if (l < n) {
            const int s = csr_src[base + l];
            sL[l] = s;
            const float4 as = *(const float4*)(al_s1 + s * 4);
            float t0 = as.x + ad.x; t0 = t0 > 0.f ? t0 : NEG_SLOPE * t0;
            float t1 = as.y + ad.y; t1 = t1 > 0.f ? t1 : NEG_SLOPE * t1;
            float t2 = as.z + ad.z; t2 = t2 > 0.f ? t2 : NEG_SLOPE * t2;
            float t3 = as.w + ad.w; t3 = t3 > 0.f ? t3 : NEG_SLOPE * t3;
            wL[l][0] = __expf(t0); wL[l][1] = __expf(t2);
            wL[l][2] = __expf(t1); wL[l][3] = __expf(t3);
        }
        __syncthreads();
        for (int i = 0; i < n; ++i) {
            const int src = sL[i];                               // broadcast
            const float2 w2 = *(const float2*)&wL[i][half * 2];  // (wA,wB)
            const unsigned int* hrow = H1b + (size_t)src * (F1 / 2);
            const unsigned int u1 = hrow[l];
            const unsigned int u2 = hrow[64 + l];
            a0 += w2.x * bf_lo(u1); a1 += w2.x * bf_hi(u1);
            a2 += w2.y * bf_lo(u2); a3 += w2.y * bf_hi(u2);
            denA += w2.x; denB += w2.y;
        }
        __syncthreads();
    }
    const float rA = 1.f / (denA + 1e-16f);
    const float rB = 1.f / (denB + 1e-16f);
    const float2 bA = *(const float2*)(b1 + 2 * l);
    const float2 bB = *(const float2*)(b1 + 128 + 2 * l);
    float v0 = a0 * rA + bA.x; v0 = v0 > 0.f ? v0 : 0.f;
    float v1 = a1 * rA + bA.y; v1 = v1 > 0.f ? v1 : 0.f;
    float v2 = a2 * rB + bB.x; v2 = v2 > 0.f ? v2 : 0.f;
    float v3 = a3 * rB + bB.y; v3 = v3 > 0.f ? v3 : 0.f;
    unsigned int* orow = out1b + (size_t)dst * (F1 / 2);
    orow[l]      = pack_bf2(v0, v1);
    orow[64 + l] = pack_bf2(v2, v3);
}

// ---------------------------------------------------------------------------
// GEMM2 via MFMA + fused layer-2 logits (H=1: reduce over all 64 cols needs
// a cross-wave LDS combine). Block = 16 nodes, 4 waves; wave w owns n-tile w.
// ---------------------------------------------------------------------------
__global__ __launch_bounds__(256) void gemm2_mfma(
    const short* __restrict__ out1s, const short* __restrict__ W2p,
    const float* __restrict__ a_src2, const float* __restrict__ a_dst2,
    unsigned short* __restrict__ H2b,
    float* __restrict__ al_s2, float* __restrict__ al_d2)
{
    const int m0 = blockIdx.x * 16;
    const int w = threadIdx.x >> 6;
    const int l = threadIdx.x & 63;
    const int q = l >> 4, r = l & 15;
    floatx4 acc = {};
    const short* arow = out1s + (size_t)(m0 + r) * F1 + q * 8;
    #pragma unroll
    for (int kt = 0; kt < 8; ++kt) {
        const short8 a = *(const short8*)(arow + kt * 32);
        const short8 b = *(const short8*)(W2p + (size_t)((w * 8 + kt) * 64 + l) * 8);
        acc = __builtin_amdgcn_mfma_f32_16x16x32_bf16(a, b, acc, 0, 0, 0);
    }
    const int col = w * 16 + r;
    const float as = a_src2[col], ad = a_dst2[col];
    float ls[4], ld[4];
    #pragma unroll
    for (int reg = 0; reg < 4; ++reg) {
        H2b[(size_t)(m0 + q * 4 + reg) * HID + col] = f2bf(acc[reg]);
        ls[reg] = acc[reg] * as;
        ld[reg] = acc[reg] * ad;
    }
    #pragma unroll
    for (int reg = 0; reg < 4; ++reg) {
        #pragma unroll
        for (int off = 8; off > 0; off >>= 1) {
            ls[reg] += __shfl_down(ls[reg], off, 16);
            ld[reg] += __shfl_down(ld[reg], off, 16);
        }
    }
    __shared__ float Ls[4][16], Ld[4][16];
    if (r == 0) {
        #pragma unroll
        for (int reg = 0; reg < 4; ++reg) {
            Ls[w][q * 4 + reg] = ls[reg];
            Ld[w][q * 4 + reg] = ld[reg];
        }
    }
    __syncthreads();
    if (threadIdx.x < 16) {
        const int row = threadIdx.x;
        float s = Ls[0][row] + Ls[1][row] + Ls[2][row] + Ls[3][row];
        float d = Ld[0][row] + Ld[1][row] + Ld[2][row] + Ld[3][row];
        al_s2[m0 + row] = s;
        al_d2[m0 + row] = d;
    }
}

// ---------------------------------------------------------------------------
// Layer-2 aggregation, CSR gather (H=1), bf16 messages. Chunked LDS weight
// prepass (exp computed once per edge, not once per lane).
// ---------------------------------------------------------------------------
__global__ __launch_bounds__(64) void agg2_csr(
    const int* __restrict__ rowptr, const int* __restrict__ csr_src,
    const float* __restrict__ al_s2, const float* __restrict__ al_d2,
    const unsigned short* __restrict__ H2b, float* __restrict__ out2)
{
    const int dst = blockIdx.x;
    const int c = threadIdx.x;
    const int beg = rowptr[dst], end = rowptr[dst + 1];
    __shared__ int   sL[CHUNK];
    __shared__ float wL[CHUNK];
    const float ad = al_d2[dst];
    float acc = 0.f, den = 0.f;
    for (int base = beg; base < end; base += CHUNK) {
        const int n = min(CHUNK, end - base);
        if (c < n) {
            const int s = csr_src[base + c];
            sL[c] = s;
            float t = al_s2[s] + ad;
            t = t > 0.f ? t : NEG_SLOPE * t;
            wL[c] = __expf(t);
        }
        __syncthreads();
        for (int i = 0; i < n; ++i) {
            const int src = sL[i];
            const float w = wL[i];
            acc += w * bf1(H2b[(size_t)src * HID + c]);
            den += w;
        }
        __syncthreads();
    }
    out2[(size_t)dst * HID + c] = acc / (den + 1e-16f);
}

// ---------------------------------------------------------------------------
// Pool (sorted-batch binary search) + FC + log_softmax. b2 folded as count*b2.
// ---------------------------------------------------------------------------
__global__ __launch_bounds__(64) void pool_fc_kernel(
    const float* __restrict__ out2, const float* __restrict__ b2,
    const int* __restrict__ batch,
    const float* __restrict__ fc_w, const float* __restrict__ fc_b,
    float* __restrict__ out)
{
    const int g = blockIdx.x;
    const int c = threadIdx.x;
    __shared__ int se[2];
    if (c < 2) {
        const int target = g + c;  // lower_bound(batch, target)
        int lo = 0, hi = N_NODES;
        while (lo < hi) { int mid = (lo + hi) >> 1; if (batch[mid] < target) lo = mid + 1; else hi = mid; }
        se[c] = lo;
    }
    __syncthreads();
    const int start = se[0], end = se[1];
    float acc = 0.f;
    for (int n = start; n < end; ++n)
        acc += out2[(size_t)n * HID + c];
    acc += (float)(end - start) * b2[c];
    __shared__ float pooled[HID];
    pooled[c] = acc;
    __syncthreads();
    __shared__ float logits[OUT_CH];
    if (c < OUT_CH) {
        float l = fc_b[c];
        #pragma unroll
        for (int k = 0; k < HID; ++k) l += pooled[k] * fc_w[k * OUT_CH + c];
        logits[c] = l;
    }
    __syncthreads();
    if (c == 0) {
        float m = logits[0];
        #pragma unroll
        for (int j2 = 1; j2 < OUT_CH; ++j2) m = fmaxf(m, logits[j2]);
        float s = 0.f;
        #pragma unroll
        for (int j2 = 0; j2 < OUT_CH; ++j2) s += __expf(logits[j2] - m);
        const float lse = m + __logf(s);
        #pragma unroll
        for (int j2 = 0; j2 < OUT_CH; ++j2) out[g * OUT_CH + j2] = logits[j2] - lse;
    }
}

// ---------------------------------------------------------------------------
// Workspace ≈ 90 MB (round-0 layout used ~131 MB and ran fine)
// ---------------------------------------------------------------------------

extern "C" void kernel_launch(void* const* d_in, const int* in_sizes, int n_in,
                              void* d_out, int out_size, void* d_ws, size_t ws_size,
                              hipStream_t stream)
{
    const float* x      = (const float*)d_in[0];
    const int*   ei     = (const int*)  d_in[1];   // [2, 800000] flat: src row, dst row
    const int*   batch  = (const int*)  d_in[2];
    const float* W1     = (const float*)d_in[3];
    const float* a_src1 = (const float*)d_in[4];
    const float* a_dst1 = (const float*)d_in[5];
    const float* b1     = (const float*)d_in[6];
    const float* W2     = (const float*)d_in[7];
    const float* a_src2 = (const float*)d_in[8];
    const float* a_dst2 = (const float*)d_in[9];
    const float* b2     = (const float*)d_in[10];
    const float* fc_w   = (const float*)d_in[11];
    const float* fc_b   = (const float*)d_in[12];
    float* out = (float*)d_out;

    char* ws = (char*)d_ws;
    size_t off = 0;
    auto alloc_b = [&](size_t bytes) { void* p = (void*)(ws + off); off += (bytes + 15) & ~15ull; return p; };

    unsigned short* H1b  = (unsigned short*)alloc_b((size_t)N_NODES * F1 * 2);     // 25.6 MB
    unsigned int*   out1b= (unsigned int*)  alloc_b((size_t)N_NODES * (F1/2) * 4); // 25.6 MB
    float* al_s1  = (float*)alloc_b((size_t)N_NODES * HEADS * 4);
    float* al_d1  = (float*)alloc_b((size_t)N_NODES * HEADS * 4);
    unsigned short* H2b  = (unsigned short*)alloc_b((size_t)N_NODES * HID * 2);    // 6.4 MB
    float* al_s2  = (float*)alloc_b((size_t)N_NODES * 4);
    float* al_d2  = (float*)alloc_b((size_t)N_NODES * 4);
    float* out2   = (float*)alloc_b((size_t)N_NODES * HID * 4);                    // 12.8 MB
    int*   deg    = (int*)alloc_b((size_t)N_NODES * 4);
    int*   rowptr = (int*)alloc_b((size_t)(N_NODES + 1) * 4);
    int*   cursor = (int*)alloc_b((size_t)N_NODES * 4);
    int*   csr_src= (int*)alloc_b((size_t)EP * 4);                                 // 3.4 MB
    int*   blocksum = (int*)alloc_b((size_t)SCAN_B * 4);
    short* xb     = (short*)alloc_b((size_t)N_NODES * IN_CH * 2);                  // 12.8 MB
    unsigned short* W1p = (unsigned short*)alloc_b((size_t)IN_CH * F1 * 2);        // 64 KB
    unsigned short* W2p = (unsigned short*)alloc_b((size_t)F1 * HID * 2);          // 32 KB

    hipMemsetAsync(deg, 0, sizeof(int) * N_NODES, stream);

    // Prep (independent of CSR)
    conv_x <<<(N_NODES * IN_CH / 4) / 256, 256, 0, stream>>>((const float4*)x, (uint2*)xb);
    pack_w1<<<16, 256, 0, stream>>>(W1, W1p);
    pack_w2<<<8, 256, 0, stream>>>(W2, W2p);

    // CSR build (two-pass parallel scan)
    csr_count  <<<(EP + 255) / 256, 256, 0, stream>>>(ei, deg);
    csr_scan1  <<<SCAN_B, 256, 0, stream>>>(deg, blocksum);
    csr_scan2  <<<SCAN_B, 256, 0, stream>>>(deg, blocksum, rowptr, cursor);
    csr_scatter<<<(EP + 255) / 256, 256, 0, stream>>>(ei, cursor, csr_src);

    // Layer 1 (logits fused into GEMM epilogue)
    gemm1_mfma<<<N_NODES / 16, 256, 0, stream>>>(xb, (const short*)W1p,
                                                 a_src1, a_dst1, H1b, al_s1, al_d1);
    agg1_csr  <<<N_NODES, 64, 0, stream>>>(rowptr, csr_src, al_s1, al_d1,
                                           (const unsigned int*)H1b, b1, out1b);

    // Layer 2 (logits fused into GEMM epilogue)
    gemm2_mfma<<<N_NODES / 16, 256, 0, stream>>>((const short*)out1b, (const short*)W2p,
                                                 a_src2, a_dst2, H2b, al_s2, al_d2);
    agg2_csr  <<<N_NODES, 64, 0, stream>>>(rowptr, csr_src, al_s2, al_d2, H2b, out2);

    // Readout
    pool_fc_kernel<<<NUM_GRAPHS, 64, 0, stream>>>(out2, b2, batch, fc_w, fc_b, out);
}

// Round 9
// 351.602 us; speedup vs baseline: 4.3582x; 1.0189x over previous
//
#include <hip/hip_runtime.h>
#include <hip/hip_bf16.h>
#include <math.h>

// Problem constants (from reference)
#define N_NODES   50000
#define N_EDGES   800000
#define EP        (N_EDGES + N_NODES)   // edges + self loops = 850000
#define IN_CH     128
#define HID       64
#define HEADS     4
#define F1        (HEADS * HID)         // 256
#define OUT_CH    10
#define NUM_GRAPHS 500
#define NEG_SLOPE 0.2f
#define CHUNK     64                     // edges staged per LDS prepass

typedef __attribute__((ext_vector_type(8))) short short8;   // 8 bf16 (4 VGPRs)
typedef __attribute__((ext_vector_type(4))) float floatx4;  // MFMA C/D

// bf16 pack/unpack helpers (RNE)
__device__ __forceinline__ unsigned short f2bf(float f) {
    unsigned int u = __float_as_uint(f);
    u += 0x7FFFu + ((u >> 16) & 1u);
    return (unsigned short)(u >> 16);
}
__device__ __forceinline__ unsigned int pack_bf2(float lo, float hi) {
    return (unsigned int)f2bf(lo) | ((unsigned int)f2bf(hi) << 16);
}
__device__ __forceinline__ float bf_lo(unsigned int u) { return __uint_as_float(u << 16); }
__device__ __forceinline__ float bf_hi(unsigned int u) { return __uint_as_float(u & 0xFFFF0000u); }

// ---------------------------------------------------------------------------
// CSR build: histogram of dst, two-pass parallel scan, scatter src indices.
// ---------------------------------------------------------------------------
__global__ void csr_count(const int* __restrict__ ei, int* __restrict__ deg)
{
    const int e = blockIdx.x * blockDim.x + threadIdx.x;
    if (e >= EP) return;
    const int dst = (e < N_EDGES) ? ei[N_EDGES + e] : e - N_EDGES;
    atomicAdd(&deg[dst], 1);
}

#define SCAN_B 196                       // ceil(50000 / 256)
__global__ __launch_bounds__(256) void csr_scan1(
    const int* __restrict__ deg, int* __restrict__ blocksum)
{
    const int b = blockIdx.x, t = threadIdx.x;
    const int i = b * 256 + t;
    __shared__ int sm[256];
    sm[t] = (i < N_NODES) ? deg[i] : 0;
    __syncthreads();
    for (int off = 128; off > 0; off >>= 1) {
        if (t < off) sm[t] += sm[t + off];
        __syncthreads();
    }
    if (t == 0) blocksum[b] = sm[0];
}
__global__ __launch_bounds__(256) void csr_scan2(
    const int* __restrict__ deg, const int* __restrict__ blocksum,
    int* __restrict__ rowptr, int* __restrict__ cursor)
{
    const int b = blockIdx.x, t = threadIdx.x;
    __shared__ int sm[256];
    sm[t] = (t < b) ? blocksum[t] : 0;     // b < SCAN_B <= 256
    __syncthreads();
    for (int off = 128; off > 0; off >>= 1) {
        if (t < off) sm[t] += sm[t + off];
        __syncthreads();
    }
    const int base = sm[0];
    __syncthreads();
    const int i = b * 256 + t;
    const int d = (i < N_NODES) ? deg[i] : 0;
    sm[t] = d;
    __syncthreads();
    for (int off = 1; off < 256; off <<= 1) {   // inclusive scan
        int u = (t >= off) ? sm[t - off] : 0;
        __syncthreads();
        if (t >= off) sm[t] += u;
        __syncthreads();
    }
    const int excl = base + sm[t] - d;
    if (i < N_NODES) { rowptr[i] = excl; cursor[i] = excl; }
    if (i == N_NODES - 1) rowptr[N_NODES] = excl + d;   // == EP
}

__global__ void csr_scatter(const int* __restrict__ ei,
                            int* __restrict__ cursor, int* __restrict__ csr_src)
{
    const int e = blockIdx.x * blockDim.x + threadIdx.x;
    if (e >= EP) return;
    int src, dst;
    if (e < N_EDGES) { src = ei[e]; dst = ei[N_EDGES + e]; }
    else             { src = dst = e - N_EDGES; }
    const int pos = atomicAdd(&cursor[dst], 1);
    csr_src[pos] = src;
}

// ---------------------------------------------------------------------------
// Prep: pack W1 and W2 (fp32 row-major [K][N]) into MFMA B-fragment layout,
// bf16, one fused dispatch. Layout:
// Wp[(ntile*KT + ktile)*64 + lane][j] = W[ktile*32 + (lane>>4)*8 + j][ntile*16 + (lane&15)]
// ---------------------------------------------------------------------------
__global__ void pack_w(const float* __restrict__ W1, unsigned short* __restrict__ W1p,
                       const float* __restrict__ W2, unsigned short* __restrict__ W2p)
{
    const int gid = blockIdx.x * blockDim.x + threadIdx.x;   // < 4096 + 2048
    if (gid < 4096) {                                        // W1: 16 nt x 4 kt x 64
        const int t = gid >> 8, kt = (gid >> 6) & 3, l = gid & 63;
        const int col = t * 16 + (l & 15);
        unsigned short* o = W1p + (size_t)((t * 4 + kt) * 64 + l) * 8;
        #pragma unroll
        for (int j = 0; j < 8; ++j) {
            const int k = kt * 32 + (l >> 4) * 8 + j;
            o[j] = f2bf(W1[k * F1 + col]);
        }
    } else {                                                 // W2: 4 nt x 8 kt x 64
        const int g2 = gid - 4096;
        const int t = g2 >> 9, kt = (g2 >> 6) & 7, l = g2 & 63;
        const int col = t * 16 + (l & 15);
        unsigned short* o = W2p + (size_t)((t * 8 + kt) * 64 + l) * 8;
        #pragma unroll
        for (int j = 0; j < 8; ++j) {
            const int k = kt * 32 + (l >> 4) * 8 + j;
            o[j] = f2bf(W2[k * HID + col]);
        }
    }
}

// ---------------------------------------------------------------------------
// GEMM1 via MFMA + fused layer-1 logits. Reads fp32 x directly, packs bf16
// A-fragments in-register (conv_x kernel eliminated). Block = 16 nodes,
// 4 waves; wave w owns cols w*64..w*64+63 = exactly head w, so logits reduce
// within the wave (width-16 shuffle).
// ---------------------------------------------------------------------------
__global__ __launch_bounds__(256) void gemm1_mfma(
    const float* __restrict__ x, const short* __restrict__ W1p,
    const float* __restrict__ a_src1, const float* __restrict__ a_dst1,
    unsigned short* __restrict__ H1b,
    float* __restrict__ al_s1, float* __restrict__ al_d1)
{
    const int m0 = blockIdx.x * 16;
    const int w = threadIdx.x >> 6;
    const int l = threadIdx.x & 63;
    const int q = l >> 4, r = l & 15;
    floatx4 acc[4] = {};
    const float* arow = x + (size_t)(m0 + r) * IN_CH + q * 8;
    #pragma unroll
    for (int kt = 0; kt < 4; ++kt) {
        const float4 f0 = *(const float4*)(arow + kt * 32);
        const float4 f1 = *(const float4*)(arow + kt * 32 + 4);
        union { uint4 u; short8 s; } a;
        a.u = make_uint4(pack_bf2(f0.x, f0.y), pack_bf2(f0.z, f0.w),
                         pack_bf2(f1.x, f1.y), pack_bf2(f1.z, f1.w));
        #pragma unroll
        for (int t = 0; t < 4; ++t) {
            const int nt = w * 4 + t;
            const short8 b = *(const short8*)(W1p + (size_t)((nt * 4 + kt) * 64 + l) * 8);
            acc[t] = __builtin_amdgcn_mfma_f32_16x16x32_bf16(a.s, b, acc[t], 0, 0, 0);
        }
    }
    float ls[4] = {0.f, 0.f, 0.f, 0.f}, ld[4] = {0.f, 0.f, 0.f, 0.f};
    #pragma unroll
    for (int t = 0; t < 4; ++t) {
        const int col = (w * 4 + t) * 16 + r;
        const float as = a_src1[col], ad = a_dst1[col];
        #pragma unroll
        for (int reg = 0; reg < 4; ++reg) {
            H1b[(size_t)(m0 + q * 4 + reg) * F1 + col] = f2bf(acc[t][reg]);
            ls[reg] += acc[t][reg] * as;
            ld[reg] += acc[t][reg] * ad;
        }
    }
    #pragma unroll
    for (int reg = 0; reg < 4; ++reg) {
        #pragma unroll
        for (int off = 8; off > 0; off >>= 1) {     // reduce over 16 cols
            ls[reg] += __shfl_down(ls[reg], off, 16);
            ld[reg] += __shfl_down(ld[reg], off, 16);
        }
    }
    if (r == 0) {
        #pragma unroll
        for (int reg = 0; reg < 4; ++reg) {
            const int n = m0 + q * 4 + reg;
            al_s1[n * HEADS + w] = ls[reg];
            al_d1[n * HEADS + w] = ld[reg];
        }
    }
}

// ---------------------------------------------------------------------------
// Layer-1 aggregation, CSR gather. One wave per dst. Lane l owns channels
// 4l..4l+3 (all in head l>>4): ONE dwordx2 load per edge (was 2 dwords),
// one weight broadcast per 16 lanes, one den. LDS chunk prepass computes the
// 4 head-weights per edge once. Epilogue: /den, +b1 (float4), relu, one
// dwordx2 store. out1b stays row-major bf16 (feeds gemm2 A directly).
// ---------------------------------------------------------------------------
__global__ __launch_bounds__(64) void agg1_csr(
    const int* __restrict__ rowptr, const int* __restrict__ csr_src,
    const float* __restrict__ al_s1, const float* __restrict__ al_d1,
    const uint2* __restrict__ H1b2, const float* __restrict__ b1,
    uint2* __restrict__ out1b2)
{
    const int dst = blockIdx.x;
    const int l = threadIdx.x;
    const int h = l >> 4;                       // this lane's head
    const int beg = rowptr[dst], end = rowptr[dst + 1];
    __shared__ int   sL[CHUNK];
    __shared__ float wL[CHUNK][4];
    const float4 ad = *(const float4*)(al_d1 + dst * 4);
    float a0 = 0.f, a1 = 0.f, a2 = 0.f, a3 = 0.f, den = 0.f;
    for (int base = beg; base < end; base += CHUNK) {
        const int n = min(CHUNK, end - base);
        if (l < n) {
            const int s = csr_src[base + l];
            sL[l] = s;
            const float4 as = *(const float4*)(al_s1 + s * 4);
            float t0 = as.x + ad.x; t0 = t0 > 0.f ? t0 : NEG_SLOPE * t0;
            float t1 = as.y + ad.y; t1 = t1 > 0.f ? t1 : NEG_SLOPE * t1;
            float t2 = as.z + ad.z; t2 = t2 > 0.f ? t2 : NEG_SLOPE * t2;
            float t3 = as.w + ad.w; t3 = t3 > 0.f ? t3 : NEG_SLOPE * t3;
            wL[l][0] = __expf(t0); wL[l][1] = __expf(t1);
            wL[l][2] = __expf(t2); wL[l][3] = __expf(t3);
        }
        __syncthreads();
        for (int i = 0; i < n; ++i) {
            const int src = sL[i];               // wave-uniform broadcast
            const float wt = wL[i][h];           // broadcast per 16 lanes
            const uint2 u = H1b2[(size_t)src * (F1 / 4) + l];   // ch 4l..4l+3
            a0 += wt * bf_lo(u.x); a1 += wt * bf_hi(u.x);
            a2 += wt * bf_lo(u.y); a3 += wt * bf_hi(u.y);
            den += wt;
        }
        __syncthreads();
    }
    const float rcp = 1.f / (den + 1e-16f);
    const float4 bb = *(const float4*)(b1 + 4 * l);
    float v0 = a0 * rcp + bb.x; v0 = v0 > 0.f ? v0 : 0.f;
    float v1 = a1 * rcp + bb.y; v1 = v1 > 0.f ? v1 : 0.f;
    float v2 = a2 * rcp + bb.z; v2 = v2 > 0.f ? v2 : 0.f;
    float v3 = a3 * rcp + bb.w; v3 = v3 > 0.f ? v3 : 0.f;
    out1b2[(size_t)dst * (F1 / 4) + l] = make_uint2(pack_bf2(v0, v1), pack_bf2(v2, v3));
}

// ---------------------------------------------------------------------------
// GEMM2 via MFMA + fused layer-2 logits (H=1: cross-wave LDS combine).
// Block = 16 nodes, 4 waves; wave w owns n-tile w.
// ---------------------------------------------------------------------------
__global__ __launch_bounds__(256) void gemm2_mfma(
    const short* __restrict__ out1s, const short* __restrict__ W2p,
    const float* __restrict__ a_src2, const float* __restrict__ a_dst2,
    unsigned short* __restrict__ H2b,
    float* __restrict__ al_s2, float* __restrict__ al_d2)
{
    const int m0 = blockIdx.x * 16;
    const int w = threadIdx.x >> 6;
    const int l = threadIdx.x & 63;
    const int q = l >> 4, r = l & 15;
    floatx4 acc = {};
    const short* arow = out1s + (size_t)(m0 + r) * F1 + q * 8;
    #pragma unroll
    for (int kt = 0; kt < 8; ++kt) {
        const short8 a = *(const short8*)(arow + kt * 32);
        const short8 b = *(const short8*)(W2p + (size_t)((w * 8 + kt) * 64 + l) * 8);
        acc = __builtin_amdgcn_mfma_f32_16x16x32_bf16(a, b, acc, 0, 0, 0);
    }
    const int col = w * 16 + r;
    const float as = a_src2[col], ad = a_dst2[col];
    float ls[4], ld[4];
    #pragma unroll
    for (int reg = 0; reg < 4; ++reg) {
        H2b[(size_t)(m0 + q * 4 + reg) * HID + col] = f2bf(acc[reg]);
        ls[reg] = acc[reg] * as;
        ld[reg] = acc[reg] * ad;
    }
    #pragma unroll
    for (int reg = 0; reg < 4; ++reg) {
        #pragma unroll
        for (int off = 8; off > 0; off >>= 1) {
            ls[reg] += __shfl_down(ls[reg], off, 16);
            ld[reg] += __shfl_down(ld[reg], off, 16);
        }
    }
    __shared__ float Ls[4][16], Ld[4][16];
    if (r == 0) {
        #pragma unroll
        for (int reg = 0; reg < 4; ++reg) {
            Ls[w][q * 4 + reg] = ls[reg];
            Ld[w][q * 4 + reg] = ld[reg];
        }
    }
    __syncthreads();
    if (threadIdx.x < 16) {
        const int row = threadIdx.x;
        al_s2[m0 + row] = Ls[0][row] + Ls[1][row] + Ls[2][row] + Ls[3][row];
        al_d2[m0 + row] = Ld[0][row] + Ld[1][row] + Ld[2][row] + Ld[3][row];
    }
}

// ---------------------------------------------------------------------------
// Layer-2 aggregation, CSR gather (H=1). Quarter-wave scheme: 4 edges in
// flight per iteration; lane l handles channels 4*(l&15)..+3 of edge
// i+(l>>4) via one dwordx2 (was 64 x 2-byte ushort loads per edge).
// Cross-quarter shfl_xor reduction; lanes 0..15 store float4.
// ---------------------------------------------------------------------------
__global__ __launch_bounds__(64) void agg2_csr(
    const int* __restrict__ rowptr, const int* __restrict__ csr_src,
    const float* __restrict__ al_s2, const float* __restrict__ al_d2,
    const uint2* __restrict__ H2b2, float* __restrict__ out2)
{
    const int dst = blockIdx.x;
    const int l = threadIdx.x;
    const int qt = l >> 4, j = l & 15;
    const int beg = rowptr[dst], end = rowptr[dst + 1];
    __shared__ int   sL[CHUNK];
    __shared__ float wL[CHUNK];
    const float ad = al_d2[dst];
    float a0 = 0.f, a1 = 0.f, a2 = 0.f, a3 = 0.f, den = 0.f;
    for (int base = beg; base < end; base += CHUNK) {
        const int n = min(CHUNK, end - base);
        if (l < n) {
            const int s = csr_src[base + l];
            sL[l] = s;
            float t = al_s2[s] + ad;
            t = t > 0.f ? t : NEG_SLOPE * t;
            wL[l] = __expf(t);
        } else {                      // pad: weight 0, safe row 0
            sL[l] = 0;
            wL[l] = 0.f;
        }
        __syncthreads();
        for (int i = 0; i < n; i += 4) {
            const int src = sL[i + qt];
            const float wt = wL[i + qt];
            const uint2 u = H2b2[(size_t)src * (HID / 4) + j];   // ch 4j..4j+3
            a0 += wt * bf_lo(u.x); a1 += wt * bf_hi(u.x);
            a2 += wt * bf_lo(u.y); a3 += wt * bf_hi(u.y);
            den += wt;
        }
        __syncthreads();
    }
    // reduce the 4 quarter-wave partials (edge subsets) per channel
    #pragma unroll
    for (int m = 16; m <= 32; m <<= 1) {
        a0 += __shfl_xor(a0, m, 64);
        a1 += __shfl_xor(a1, m, 64);
        a2 += __shfl_xor(a2, m, 64);
        a3 += __shfl_xor(a3, m, 64);
        den += __shfl_xor(den, m, 64);
    }
    if (l < 16) {
        const float rcp = 1.f / (den + 1e-16f);
        *(float4*)(out2 + (size_t)dst * HID + 4 * j) =
            make_float4(a0 * rcp, a1 * rcp, a2 * rcp, a3 * rcp);
    }
}

// ---------------------------------------------------------------------------
// Pool (sorted-batch binary search) + FC + log_softmax. b2 folded as count*b2.
// ---------------------------------------------------------------------------
__global__ __launch_bounds__(64) void pool_fc_kernel(
    const float* __restrict__ out2, const float* __restrict__ b2,
    const int* __restrict__ batch,
    const float* __restrict__ fc_w, const float* __restrict__ fc_b,
    float* __restrict__ out)
{
    const int g = blockIdx.x;
    const int c = threadIdx.x;
    __shared__ int se[2];
    if (c < 2) {
        const int target = g + c;  // lower_bound(batch, target)
        int lo = 0, hi = N_NODES;
        while (lo < hi) { int mid = (lo + hi) >> 1; if (batch[mid] < target) lo = mid + 1; else hi = mid; }
        se[c] = lo;
    }
    __syncthreads();
    const int start = se[0], end = se[1];
    float acc = 0.f;
    for (int n = start; n < end; ++n)
        acc += out2[(size_t)n * HID + c];
    acc += (float)(end - start) * b2[c];
    __shared__ float pooled[HID];
    pooled[c] = acc;
    __syncthreads();
    __shared__ float logits[OUT_CH];
    if (c < OUT_CH) {
        float l = fc_b[c];
        #pragma unroll
        for (int k = 0; k < HID; ++k) l += pooled[k] * fc_w[k * OUT_CH + c];
        logits[c] = l;
    }
    __syncthreads();
    if (c == 0) {
        float m = logits[0];
        #pragma unroll
        for (int j2 = 1; j2 < OUT_CH; ++j2) m = fmaxf(m, logits[j2]);
        float s = 0.f;
        #pragma unroll
        for (int j2 = 0; j2 < OUT_CH; ++j2) s += __expf(logits[j2] - m);
        const float lse = m + __logf(s);
        #pragma unroll
        for (int j2 = 0; j2 < OUT_CH; ++j2) out[g * OUT_CH + j2] = logits[j2] - lse;
    }
}

// ---------------------------------------------------------------------------
// Workspace ≈ 77 MB (xb eliminated; round-0 layout used ~131 MB and ran fine)
// ---------------------------------------------------------------------------

extern "C" void kernel_launch(void* const* d_in, const int* in_sizes, int n_in,
                              void* d_out, int out_size, void* d_ws, size_t ws_size,
                              hipStream_t stream)
{
    const float* x      = (const float*)d_in[0];
    const int*   ei     = (const int*)  d_in[1];   // [2, 800000] flat: src row, dst row
    const int*   batch  = (const int*)  d_in[2];
    const float* W1     = (const float*)d_in[3];
    const float* a_src1 = (const float*)d_in[4];
    const float* a_dst1 = (const float*)d_in[5];
    const float* b1     = (const float*)d_in[6];
    const float* W2     = (const float*)d_in[7];
    const float* a_src2 = (const float*)d_in[8];
    const float* a_dst2 = (const float*)d_in[9];
    const float* b2     = (const float*)d_in[10];
    const float* fc_w   = (const float*)d_in[11];
    const float* fc_b   = (const float*)d_in[12];
    float* out = (float*)d_out;

    char* ws = (char*)d_ws;
    size_t off = 0;
    auto alloc_b = [&](size_t bytes) { void* p = (void*)(ws + off); off += (bytes + 15) & ~15ull; return p; };

    unsigned short* H1b  = (unsigned short*)alloc_b((size_t)N_NODES * F1 * 2);     // 25.6 MB
    unsigned int*   out1b= (unsigned int*)  alloc_b((size_t)N_NODES * (F1/2) * 4); // 25.6 MB
    float* al_s1  = (float*)alloc_b((size_t)N_NODES * HEADS * 4);
    float* al_d1  = (float*)alloc_b((size_t)N_NODES * HEADS * 4);
    unsigned short* H2b  = (unsigned short*)alloc_b((size_t)N_NODES * HID * 2);    // 6.4 MB
    float* al_s2  = (float*)alloc_b((size_t)N_NODES * 4);
    float* al_d2  = (float*)alloc_b((size_t)N_NODES * 4);
    float* out2   = (float*)alloc_b((size_t)N_NODES * HID * 4);                    // 12.8 MB
    int*   deg    = (int*)alloc_b((size_t)N_NODES * 4);
    int*   rowptr = (int*)alloc_b((size_t)(N_NODES + 1) * 4);
    int*   cursor = (int*)alloc_b((size_t)N_NODES * 4);
    int*   csr_src= (int*)alloc_b((size_t)EP * 4);                                 // 3.4 MB
    int*   blocksum = (int*)alloc_b((size_t)SCAN_B * 4);
    unsigned short* W1p = (unsigned short*)alloc_b((size_t)IN_CH * F1 * 2);        // 64 KB
    unsigned short* W2p = (unsigned short*)alloc_b((size_t)F1 * HID * 2);          // 32 KB

    hipMemsetAsync(deg, 0, sizeof(int) * N_NODES, stream);

    // Prep
    pack_w<<<24, 256, 0, stream>>>(W1, W1p, W2, W2p);

    // CSR build (two-pass parallel scan)
    csr_count  <<<(EP + 255) / 256, 256, 0, stream>>>(ei, deg);
    csr_scan1  <<<SCAN_B, 256, 0, stream>>>(deg, blocksum);
    csr_scan2  <<<SCAN_B, 256, 0, stream>>>(deg, blocksum, rowptr, cursor);
    csr_scatter<<<(EP + 255) / 256, 256, 0, stream>>>(ei, cursor, csr_src);

    // Layer 1 (logits fused into GEMM epilogue; x converted in-register)
    gemm1_mfma<<<N_NODES / 16, 256, 0, stream>>>(x, (const short*)W1p,
                                                 a_src1, a_dst1, H1b, al_s1, al_d1);
    agg1_csr  <<<N_NODES, 64, 0, stream>>>(rowptr, csr_src, al_s1, al_d1,
                                           (const uint2*)H1b, b1, (uint2*)out1b);

    // Layer 2 (logits fused into GEMM epilogue)
    gemm2_mfma<<<N_NODES / 16, 256, 0, stream>>>((const short*)out1b, (const short*)W2p,
                                                 a_src2, a_dst2, H2b, al_s2, al_d2);
    agg2_csr  <<<N_NODES, 64, 0, stream>>>(rowptr, csr_src, al_s2, al_d2,
                                           (const uint2*)H2b, out2);

    // Readout
    pool_fc_kernel<<<NUM_GRAPHS, 64, 0, stream>>>(out2, b2, batch, fc_w, fc_b, out);
}